// Round 1
// baseline (479.471 us; speedup 1.0000x reference)
//
#include <hip/hip_runtime.h>

#define BS 256

// ---------------- degree / CSR construction ----------------

__global__ void k_init_deg(int* __restrict__ deg, int n) {
    int i = blockIdx.x * blockDim.x + threadIdx.x;
    if (i < n) deg[i] = 1;  // self-loop
}

__global__ void k_deg(const int* __restrict__ dst, int* __restrict__ deg, int E) {
    int e = blockIdx.x * blockDim.x + threadIdx.x;
    if (e < E) atomicAdd(&deg[dst[e]], 1);
}

__global__ void k_block_sums(const int* __restrict__ deg, int* __restrict__ bsum, int n) {
    int t = threadIdx.x;
    int base = blockIdx.x * (BS * 8) + t * 8;
    int s = 0;
#pragma unroll
    for (int j = 0; j < 8; ++j) {
        int i = base + j;
        if (i < n) s += deg[i];
    }
#pragma unroll
    for (int off = 32; off > 0; off >>= 1) s += __shfl_down(s, off);
    __shared__ int ws[BS / 64];
    int lane = t & 63, w = t >> 6;
    if (lane == 0) ws[w] = s;
    __syncthreads();
    if (t == 0) {
        int tot = 0;
        for (int q = 0; q < BS / 64; ++q) tot += ws[q];
        bsum[blockIdx.x] = tot;
    }
}

// single wave; nb <= 64 (n=100000 -> nb=49)
__global__ void k_spine(const int* __restrict__ bsum, int* __restrict__ boff,
                        int* __restrict__ total_out, int nb) {
    int t = threadIdx.x;
    int v = (t < nb) ? bsum[t] : 0;
    int incl = v;
#pragma unroll
    for (int off = 1; off < 64; off <<= 1) {
        int u = __shfl_up(incl, off);
        if (t >= off) incl += u;
    }
    if (t < nb) boff[t] = incl - v;  // exclusive
    if (t == 63) *total_out = incl;  // rowptr[n]
}

__global__ void k_scan_final(const int* __restrict__ deg, const int* __restrict__ boff,
                             int* __restrict__ rowptr, int* __restrict__ cursor,
                             float* __restrict__ dinv, int n) {
    int t = threadIdx.x;
    int base = blockIdx.x * (BS * 8) + t * 8;
    int epre[8];
    int run = 0;
#pragma unroll
    for (int j = 0; j < 8; ++j) {
        epre[j] = run;
        int i = base + j;
        if (i < n) run += deg[i];
    }
    int lane = t & 63, w = t >> 6;
    int incl = run;
#pragma unroll
    for (int off = 1; off < 64; off <<= 1) {
        int u = __shfl_up(incl, off);
        if (lane >= off) incl += u;
    }
    __shared__ int ws[BS / 64];
    if (lane == 63) ws[w] = incl;
    __syncthreads();
    int woff = 0;
    for (int q = 0; q < w; ++q) woff += ws[q];
    int texcl = boff[blockIdx.x] + woff + (incl - run);
#pragma unroll
    for (int j = 0; j < 8; ++j) {
        int i = base + j;
        if (i < n) {
            int o = texcl + epre[j];
            rowptr[i] = o;
            cursor[i] = o;
            dinv[i] = rsqrtf((float)deg[i]);
        }
    }
}

__global__ void k_fill(const int* __restrict__ src, const int* __restrict__ dst,
                       int* __restrict__ cursor, int* __restrict__ csr, int E, int n) {
    int e = blockIdx.x * blockDim.x + threadIdx.x;
    int tot = E + n;
    if (e >= tot) return;
    int s, d;
    if (e < E) { s = src[e]; d = dst[e]; }
    else       { s = e - E; d = s; }
    int pos = atomicAdd(&cursor[d], 1);
    csr[pos] = s;
}

// ---------------- GEMM: H[i][c] = dinv[i] * sum_k act(X[i][k]) * W[k][c] ----------------
// act = relu(x + bias[k]) when FUSE, else identity.
// Block: 256 threads; tile ROWS rows; W fully in LDS; x tile XOR-swizzled (k4 ^= r&7)
// so compute reads and W reads are bank-conflict-free (<=2-way).

template <int K, int COLS, bool FUSE>
__global__ __launch_bounds__(BS) void k_gemm(const float* __restrict__ X,
                                             const float* __restrict__ W,
                                             const float* __restrict__ bias,
                                             const float* __restrict__ dscale,
                                             float* __restrict__ H, int n) {
    constexpr int COLS4 = COLS / 4;
    constexpr int TY = BS / COLS4;
    constexpr int ROWS = 4 * TY;
    constexpr int K4 = K / 4;
    __shared__ float sW[K * COLS];
    __shared__ float sX[ROWS * K];
    int tid = threadIdx.x;
    for (int idx = tid; idx < K * COLS4; idx += BS)
        ((float4*)sW)[idx] = ((const float4*)W)[idx];
    int ntiles = (n + ROWS - 1) / ROWS;
    int tx = tid % COLS4, ty = tid / COLS4;
    for (int tile = blockIdx.x; tile < ntiles; tile += gridDim.x) {
        int row0 = tile * ROWS;
        __syncthreads();  // protect sX reuse (and sW before first compute)
        for (int idx = tid; idx < ROWS * K4; idx += BS) {
            int r = idx / K4, k4 = idx % K4;
            int row = row0 + r;
            float4 v = make_float4(0.f, 0.f, 0.f, 0.f);
            if (row < n) {
                v = ((const float4*)X)[row * K4 + k4];
                if (FUSE) {
                    float4 b = ((const float4*)bias)[k4];
                    v.x = fmaxf(v.x + b.x, 0.f);
                    v.y = fmaxf(v.y + b.y, 0.f);
                    v.z = fmaxf(v.z + b.z, 0.f);
                    v.w = fmaxf(v.w + b.w, 0.f);
                }
            }
            *(float4*)&sX[r * K + ((k4 ^ (r & 7)) << 2)] = v;
        }
        __syncthreads();
        float acc[4][4];
#pragma unroll
        for (int s = 0; s < 4; ++s)
#pragma unroll
            for (int c = 0; c < 4; ++c) acc[s][c] = 0.f;
        for (int kk = 0; kk < K; kk += 4) {
            int k4 = kk >> 2;
            float4 w0 = *(const float4*)&sW[(kk + 0) * COLS + tx * 4];
            float4 w1 = *(const float4*)&sW[(kk + 1) * COLS + tx * 4];
            float4 w2 = *(const float4*)&sW[(kk + 2) * COLS + tx * 4];
            float4 w3 = *(const float4*)&sW[(kk + 3) * COLS + tx * 4];
#pragma unroll
            for (int s = 0; s < 4; ++s) {
                int r = ty + TY * s;
                float4 xv = *(const float4*)&sX[r * K + ((k4 ^ (ty & 7)) << 2)];
                acc[s][0] += xv.x * w0.x + xv.y * w1.x + xv.z * w2.x + xv.w * w3.x;
                acc[s][1] += xv.x * w0.y + xv.y * w1.y + xv.z * w2.y + xv.w * w3.y;
                acc[s][2] += xv.x * w0.z + xv.y * w1.z + xv.z * w2.z + xv.w * w3.z;
                acc[s][3] += xv.x * w0.w + xv.y * w1.w + xv.z * w2.w + xv.w * w3.w;
            }
        }
#pragma unroll
        for (int s = 0; s < 4; ++s) {
            int row = row0 + ty + TY * s;
            if (row < n) {
                float dv = dscale[row];
                float4 o = make_float4(acc[s][0] * dv, acc[s][1] * dv,
                                       acc[s][2] * dv, acc[s][3] * dv);
                ((float4*)H)[row * COLS4 + tx] = o;
            }
        }
    }
}

// ---------------- Aggregation (gather-side, no atomics) ----------------
// h is pre-scaled by dinv[src]; out[i] = dinv[i] * sum_{s in row i} h[s][:]

__global__ __launch_bounds__(BS) void k_agg64(const float* __restrict__ h,
                                              const int* __restrict__ csr,
                                              const int* __restrict__ rowptr,
                                              const float* __restrict__ dinv,
                                              float* __restrict__ out, int n) {
    int gw = (blockIdx.x * BS + threadIdx.x) >> 6;
    int lane = threadIdx.x & 63;
    if (gw >= n) return;
    int b = rowptr[gw], e = rowptr[gw + 1];
    float acc = 0.f;
    for (int c = b; c < e; c += 64) {
        int m = e - c;
        if (m > 64) m = 64;
        int sv = (lane < m) ? csr[c + lane] : 0;
        int j = 0;
        for (; j + 3 < m; j += 4) {
            int s0 = __shfl(sv, j), s1 = __shfl(sv, j + 1);
            int s2 = __shfl(sv, j + 2), s3 = __shfl(sv, j + 3);
            float v0 = h[s0 * 64 + lane];
            float v1 = h[s1 * 64 + lane];
            float v2 = h[s2 * 64 + lane];
            float v3 = h[s3 * 64 + lane];
            acc += v0; acc += v1; acc += v2; acc += v3;
        }
        for (; j < m; ++j) {
            int s0 = __shfl(sv, j);
            acc += h[s0 * 64 + lane];
        }
    }
    out[gw * 64 + lane] = acc * dinv[gw];
}

// 32 features: two nodes per wave (half-wave each); adds final bias b.
__global__ __launch_bounds__(BS) void k_agg32(const float* __restrict__ h,
                                              const int* __restrict__ csr,
                                              const int* __restrict__ rowptr,
                                              const float* __restrict__ dinv,
                                              const float* __restrict__ bias,
                                              float* __restrict__ out, int n) {
    int wid = (blockIdx.x * BS + threadIdx.x) >> 6;
    int lane = threadIdx.x & 63;
    if (wid * 2 >= n) return;
    int half = lane >> 5, f = lane & 31;
    int node = wid * 2 + half;
    bool valid = node < n;
    int b = 0, e = 0;
    if (valid) { b = rowptr[node]; e = rowptr[node + 1]; }
    float acc = 0.f;
    for (int c = b; c < e; c += 32) {
        int m = e - c;
        if (m > 32) m = 32;
        int sv = (f < m) ? csr[c + f] : 0;
        int j = 0;
        for (; j + 3 < m; j += 4) {
            int s0 = __shfl(sv, j, 32), s1 = __shfl(sv, j + 1, 32);
            int s2 = __shfl(sv, j + 2, 32), s3 = __shfl(sv, j + 3, 32);
            float v0 = h[s0 * 32 + f];
            float v1 = h[s1 * 32 + f];
            float v2 = h[s2 * 32 + f];
            float v3 = h[s3 * 32 + f];
            acc += v0; acc += v1; acc += v2; acc += v3;
        }
        for (; j < m; ++j) {
            int s0 = __shfl(sv, j, 32);
            acc += h[s0 * 32 + f];
        }
    }
    if (valid) out[node * 32 + f] = acc * dinv[node] + bias[f];
}

// ---------------- launch ----------------

extern "C" void kernel_launch(void* const* d_in, const int* in_sizes, int n_in,
                              void* d_out, int out_size, void* d_ws, size_t ws_size,
                              hipStream_t stream) {
    const float* x  = (const float*)d_in[0];
    const int* eidx = (const int*)d_in[1];
    const float* W1 = (const float*)d_in[2];
    const float* b1 = (const float*)d_in[3];
    const float* W2 = (const float*)d_in[4];
    const float* b2 = (const float*)d_in[5];
    float* out = (float*)d_out;

    int n = in_sizes[0] / 128;
    int E = in_sizes[1] / 2;
    const int* srcA = eidx;
    const int* dstA = eidx + E;

    char* p = (char*)d_ws;
    auto alloc = [&](size_t bytes) {
        char* q = p;
        p += (bytes + 255) & ~(size_t)255;
        return q;
    };
    int*   deg    = (int*)alloc((size_t)n * 4);
    int*   rowptr = (int*)alloc((size_t)(n + 1) * 4);
    int*   cursor = (int*)alloc((size_t)n * 4);
    int*   bsum   = (int*)alloc(64 * 4);
    int*   boff   = (int*)alloc(64 * 4);
    float* dinv   = (float*)alloc((size_t)n * 4);
    int*   csr    = (int*)alloc((size_t)(E + n) * 4);
    float* h1     = (float*)alloc((size_t)n * 64 * 4);
    float* g1     = (float*)alloc((size_t)n * 64 * 4);
    float* h2     = (float*)alloc((size_t)n * 32 * 4);

    int nb_scan = (n + BS * 8 - 1) / (BS * 8);  // 49 for n=100000 (<=64 req'd by k_spine)

    k_init_deg<<<(n + BS - 1) / BS, BS, 0, stream>>>(deg, n);
    k_deg<<<(E + BS - 1) / BS, BS, 0, stream>>>(dstA, deg, E);
    k_block_sums<<<nb_scan, BS, 0, stream>>>(deg, bsum, n);
    k_spine<<<1, 64, 0, stream>>>(bsum, boff, rowptr + n, nb_scan);
    k_scan_final<<<nb_scan, BS, 0, stream>>>(deg, boff, rowptr, cursor, dinv, n);
    k_fill<<<(E + n + BS - 1) / BS, BS, 0, stream>>>(srcA, dstA, cursor, csr, E, n);

    // layer 1: h1 = dinv .* (x @ W1); g1 = dinv .* (A-gather h1)
    k_gemm<128, 64, false><<<(n + 63) / 64, BS, 0, stream>>>(x, W1, nullptr, dinv, h1, n);
    k_agg64<<<((size_t)n * 64 + BS - 1) / BS, BS, 0, stream>>>(h1, csr, rowptr, dinv, g1, n);

    // layer 2: h2 = dinv .* (relu(g1 + b1) @ W2); out = dinv .* (A-gather h2) + b2
    k_gemm<64, 32, true><<<(n + 127) / 128, BS, 0, stream>>>(g1, W2, b1, dinv, h2, n);
    int waves2 = (n + 1) / 2;
    k_agg32<<<((size_t)waves2 * 64 + BS - 1) / BS, BS, 0, stream>>>(h2, csr, rowptr, dinv, b2, out, n);
}

// Round 2
// 349.176 us; speedup vs baseline: 1.3732x; 1.3732x over previous
//
#include <hip/hip_runtime.h>

#define BS 256
#define BSHIFT 9                // 512 nodes per bucket
#define BNODES (1 << BSHIFT)
#define NB 256                  // bucket table size (>= ceil(100000/512)=196)
#define CHUNK 4096              // edges per block for count/scatter (16/thread)

// ---------------- bucketed CSR construction ----------------

__global__ void k_zero_buckets(int* __restrict__ bucketCount) {
    int t = threadIdx.x;
    if (t < NB) bucketCount[t] = 0;
}

__global__ __launch_bounds__(BS) void k_count(const int* __restrict__ dst,
                                              int* __restrict__ bucketCount, int E) {
    __shared__ int h[NB];
    int t = threadIdx.x;
    h[t] = 0;
    __syncthreads();
    int base = blockIdx.x * CHUNK;
#pragma unroll
    for (int j = 0; j < CHUNK / BS; ++j) {
        int e = base + j * BS + t;
        if (e < E) atomicAdd(&h[dst[e] >> BSHIFT], 1);
    }
    __syncthreads();
    if (h[t]) atomicAdd(&bucketCount[t], h[t]);
}

// 1 block, 256 threads: exclusive scan of bucketCount -> bucketBase, gcursor
__global__ void k_bucket_scan(const int* __restrict__ bucketCount,
                              int* __restrict__ bucketBase,
                              int* __restrict__ gcursor) {
    int t = threadIdx.x;
    int v = bucketCount[t];
    int incl = v;
    int lane = t & 63, w = t >> 6;
#pragma unroll
    for (int off = 1; off < 64; off <<= 1) {
        int u = __shfl_up(incl, off);
        if (lane >= off) incl += u;
    }
    __shared__ int ws[4];
    if (lane == 63) ws[w] = incl;
    __syncthreads();
    int woff = 0;
    for (int q = 0; q < w; ++q) woff += ws[q];
    int excl = woff + incl - v;
    bucketBase[t] = excl;
    gcursor[t] = excl;
    if (t == NB - 1) bucketBase[NB] = excl + v;  // == E
}

__global__ __launch_bounds__(BS) void k_scatter(const int* __restrict__ src,
                                                const int* __restrict__ dst,
                                                int* __restrict__ gcursor,
                                                int2* __restrict__ binned, int E) {
    __shared__ int h[NB];
    __shared__ int base[NB];
    int t = threadIdx.x;
    h[t] = 0;
    __syncthreads();
    int cbase = blockIdx.x * CHUNK;
    int sv[CHUNK / BS], dv[CHUNK / BS], rv[CHUNK / BS];
#pragma unroll
    for (int j = 0; j < CHUNK / BS; ++j) {
        int e = cbase + j * BS + t;
        rv[j] = -1;
        if (e < E) {
            sv[j] = src[e];
            dv[j] = dst[e];
            rv[j] = atomicAdd(&h[dv[j] >> BSHIFT], 1);
        }
    }
    __syncthreads();
    base[t] = h[t] ? atomicAdd(&gcursor[t], h[t]) : 0;
    __syncthreads();
#pragma unroll
    for (int j = 0; j < CHUNK / BS; ++j) {
        if (rv[j] >= 0) {
            int b = dv[j] >> BSHIFT;
            binned[base[b] + rv[j]] = make_int2(sv[j], dv[j]);
        }
    }
}

// one block per bucket: per-node degree from binned edges (LDS histogram)
__global__ __launch_bounds__(BS) void k_b1(const int2* __restrict__ binned,
                                           const int* __restrict__ bucketBase,
                                           int* __restrict__ deg, int n) {
    __shared__ int h[BNODES];
    int t = threadIdx.x;
    int node0 = blockIdx.x << BSHIFT;
    int nn = min(BNODES, n - node0);
#pragma unroll
    for (int i = t; i < BNODES; i += BS) h[i] = 0;
    __syncthreads();
    int eb = bucketBase[blockIdx.x], ee = bucketBase[blockIdx.x + 1];
    for (int e = eb + t; e < ee; e += BS) {
        int d = binned[e].y;
        atomicAdd(&h[d - node0], 1);
    }
    __syncthreads();
    for (int i = t; i < nn; i += BS) deg[node0 + i] = h[i] + 1;  // +1 self-loop
}

// ---------------- global scan of deg -> rowptr ----------------

__global__ void k_block_sums(const int* __restrict__ deg, int* __restrict__ bsum, int n) {
    int t = threadIdx.x;
    int base = blockIdx.x * (BS * 8) + t * 8;
    int s = 0;
#pragma unroll
    for (int j = 0; j < 8; ++j) {
        int i = base + j;
        if (i < n) s += deg[i];
    }
#pragma unroll
    for (int off = 32; off > 0; off >>= 1) s += __shfl_down(s, off);
    __shared__ int ws[BS / 64];
    int lane = t & 63, w = t >> 6;
    if (lane == 0) ws[w] = s;
    __syncthreads();
    if (t == 0) {
        int tot = 0;
        for (int q = 0; q < BS / 64; ++q) tot += ws[q];
        bsum[blockIdx.x] = tot;
    }
}

// single wave; nb <= 64 (n=100000 -> nb=49)
__global__ void k_spine(const int* __restrict__ bsum, int* __restrict__ boff,
                        int* __restrict__ total_out, int nb) {
    int t = threadIdx.x;
    int v = (t < nb) ? bsum[t] : 0;
    int incl = v;
#pragma unroll
    for (int off = 1; off < 64; off <<= 1) {
        int u = __shfl_up(incl, off);
        if (t >= off) incl += u;
    }
    if (t < nb) boff[t] = incl - v;  // exclusive
    if (t == 63) *total_out = incl;  // rowptr[n]
}

__global__ void k_scan_final(const int* __restrict__ deg, const int* __restrict__ boff,
                             int* __restrict__ rowptr, float* __restrict__ dinv, int n) {
    int t = threadIdx.x;
    int base = blockIdx.x * (BS * 8) + t * 8;
    int epre[8];
    int run = 0;
#pragma unroll
    for (int j = 0; j < 8; ++j) {
        epre[j] = run;
        int i = base + j;
        if (i < n) run += deg[i];
    }
    int lane = t & 63, w = t >> 6;
    int incl = run;
#pragma unroll
    for (int off = 1; off < 64; off <<= 1) {
        int u = __shfl_up(incl, off);
        if (lane >= off) incl += u;
    }
    __shared__ int ws[BS / 64];
    if (lane == 63) ws[w] = incl;
    __syncthreads();
    int woff = 0;
    for (int q = 0; q < w; ++q) woff += ws[q];
    int texcl = boff[blockIdx.x] + woff + (incl - run);
#pragma unroll
    for (int j = 0; j < 8; ++j) {
        int i = base + j;
        if (i < n) {
            rowptr[i] = texcl + epre[j];
            dinv[i] = rsqrtf((float)deg[i]);
        }
    }
}

// one block per bucket: fill CSR (self-loop first, then binned edges)
__global__ __launch_bounds__(BS) void k_b2(const int2* __restrict__ binned,
                                           const int* __restrict__ bucketBase,
                                           const int* __restrict__ rowptr,
                                           int* __restrict__ csr, int n) {
    __shared__ int rp[BNODES];
    __shared__ int cur[BNODES];
    int t = threadIdx.x;
    int node0 = blockIdx.x << BSHIFT;
    int nn = min(BNODES, n - node0);
#pragma unroll
    for (int i = t; i < BNODES; i += BS) cur[i] = 1;  // slot 0 = self-loop
    for (int i = t; i < nn; i += BS) {
        int r = rowptr[node0 + i];
        rp[i] = r;
        csr[r] = node0 + i;  // self-loop
    }
    __syncthreads();
    int eb = bucketBase[blockIdx.x], ee = bucketBase[blockIdx.x + 1];
    for (int e = eb + t; e < ee; e += BS) {
        int2 p = binned[e];
        int li = p.y - node0;
        int r = atomicAdd(&cur[li], 1);
        csr[rp[li] + r] = p.x;
    }
}

// ---------------- GEMM: H[i][c] = dinv[i] * sum_k act(X[i][k]) * W[k][c] ----------------

template <int K, int COLS, bool FUSE>
__global__ __launch_bounds__(BS) void k_gemm(const float* __restrict__ X,
                                             const float* __restrict__ W,
                                             const float* __restrict__ bias,
                                             const float* __restrict__ dscale,
                                             float* __restrict__ H, int n) {
    constexpr int COLS4 = COLS / 4;
    constexpr int TY = BS / COLS4;
    constexpr int ROWS = 4 * TY;
    constexpr int K4 = K / 4;
    __shared__ float sW[K * COLS];
    __shared__ float sX[ROWS * K];
    int tid = threadIdx.x;
    for (int idx = tid; idx < K * COLS4; idx += BS)
        ((float4*)sW)[idx] = ((const float4*)W)[idx];
    int ntiles = (n + ROWS - 1) / ROWS;
    int tx = tid % COLS4, ty = tid / COLS4;
    for (int tile = blockIdx.x; tile < ntiles; tile += gridDim.x) {
        int row0 = tile * ROWS;
        __syncthreads();
        for (int idx = tid; idx < ROWS * K4; idx += BS) {
            int r = idx / K4, k4 = idx % K4;
            int row = row0 + r;
            float4 v = make_float4(0.f, 0.f, 0.f, 0.f);
            if (row < n) {
                v = ((const float4*)X)[row * K4 + k4];
                if (FUSE) {
                    float4 b = ((const float4*)bias)[k4];
                    v.x = fmaxf(v.x + b.x, 0.f);
                    v.y = fmaxf(v.y + b.y, 0.f);
                    v.z = fmaxf(v.z + b.z, 0.f);
                    v.w = fmaxf(v.w + b.w, 0.f);
                }
            }
            *(float4*)&sX[r * K + ((k4 ^ (r & 7)) << 2)] = v;
        }
        __syncthreads();
        float acc[4][4];
#pragma unroll
        for (int s = 0; s < 4; ++s)
#pragma unroll
            for (int c = 0; c < 4; ++c) acc[s][c] = 0.f;
        for (int kk = 0; kk < K; kk += 4) {
            int k4 = kk >> 2;
            float4 w0 = *(const float4*)&sW[(kk + 0) * COLS + tx * 4];
            float4 w1 = *(const float4*)&sW[(kk + 1) * COLS + tx * 4];
            float4 w2 = *(const float4*)&sW[(kk + 2) * COLS + tx * 4];
            float4 w3 = *(const float4*)&sW[(kk + 3) * COLS + tx * 4];
#pragma unroll
            for (int s = 0; s < 4; ++s) {
                int r = ty + TY * s;
                float4 xv = *(const float4*)&sX[r * K + ((k4 ^ (ty & 7)) << 2)];
                acc[s][0] += xv.x * w0.x + xv.y * w1.x + xv.z * w2.x + xv.w * w3.x;
                acc[s][1] += xv.x * w0.y + xv.y * w1.y + xv.z * w2.y + xv.w * w3.y;
                acc[s][2] += xv.x * w0.z + xv.y * w1.z + xv.z * w2.z + xv.w * w3.z;
                acc[s][3] += xv.x * w0.w + xv.y * w1.w + xv.z * w2.w + xv.w * w3.w;
            }
        }
#pragma unroll
        for (int s = 0; s < 4; ++s) {
            int row = row0 + ty + TY * s;
            if (row < n) {
                float dv = dscale[row];
                float4 o = make_float4(acc[s][0] * dv, acc[s][1] * dv,
                                       acc[s][2] * dv, acc[s][3] * dv);
                ((float4*)H)[row * COLS4 + tx] = o;
            }
        }
    }
}

// ---------------- Aggregation (gather-side, no atomics) ----------------

__global__ __launch_bounds__(BS) void k_agg64(const float* __restrict__ h,
                                              const int* __restrict__ csr,
                                              const int* __restrict__ rowptr,
                                              const float* __restrict__ dinv,
                                              float* __restrict__ out, int n) {
    int gw = (blockIdx.x * BS + threadIdx.x) >> 6;
    int lane = threadIdx.x & 63;
    if (gw >= n) return;
    int b = rowptr[gw], e = rowptr[gw + 1];
    float acc = 0.f;
    for (int c = b; c < e; c += 64) {
        int m = e - c;
        if (m > 64) m = 64;
        int sv = (lane < m) ? csr[c + lane] : 0;
        int j = 0;
        for (; j + 3 < m; j += 4) {
            int s0 = __shfl(sv, j), s1 = __shfl(sv, j + 1);
            int s2 = __shfl(sv, j + 2), s3 = __shfl(sv, j + 3);
            float v0 = h[s0 * 64 + lane];
            float v1 = h[s1 * 64 + lane];
            float v2 = h[s2 * 64 + lane];
            float v3 = h[s3 * 64 + lane];
            acc += v0; acc += v1; acc += v2; acc += v3;
        }
        for (; j < m; ++j) {
            int s0 = __shfl(sv, j);
            acc += h[s0 * 64 + lane];
        }
    }
    out[gw * 64 + lane] = acc * dinv[gw];
}

__global__ __launch_bounds__(BS) void k_agg32(const float* __restrict__ h,
                                              const int* __restrict__ csr,
                                              const int* __restrict__ rowptr,
                                              const float* __restrict__ dinv,
                                              const float* __restrict__ bias,
                                              float* __restrict__ out, int n) {
    int wid = (blockIdx.x * BS + threadIdx.x) >> 6;
    int lane = threadIdx.x & 63;
    if (wid * 2 >= n) return;
    int half = lane >> 5, f = lane & 31;
    int node = wid * 2 + half;
    bool valid = node < n;
    int b = 0, e = 0;
    if (valid) { b = rowptr[node]; e = rowptr[node + 1]; }
    float acc = 0.f;
    for (int c = b; c < e; c += 32) {
        int m = e - c;
        if (m > 32) m = 32;
        int sv = (f < m) ? csr[c + f] : 0;
        int j = 0;
        for (; j + 3 < m; j += 4) {
            int s0 = __shfl(sv, j, 32), s1 = __shfl(sv, j + 1, 32);
            int s2 = __shfl(sv, j + 2, 32), s3 = __shfl(sv, j + 3, 32);
            float v0 = h[s0 * 32 + f];
            float v1 = h[s1 * 32 + f];
            float v2 = h[s2 * 32 + f];
            float v3 = h[s3 * 32 + f];
            acc += v0; acc += v1; acc += v2; acc += v3;
        }
        for (; j < m; ++j) {
            int s0 = __shfl(sv, j, 32);
            acc += h[s0 * 32 + f];
        }
    }
    if (valid) out[node * 32 + f] = acc * dinv[node] + bias[f];
}

// ---------------- launch ----------------

extern "C" void kernel_launch(void* const* d_in, const int* in_sizes, int n_in,
                              void* d_out, int out_size, void* d_ws, size_t ws_size,
                              hipStream_t stream) {
    const float* x  = (const float*)d_in[0];
    const int* eidx = (const int*)d_in[1];
    const float* W1 = (const float*)d_in[2];
    const float* b1 = (const float*)d_in[3];
    const float* W2 = (const float*)d_in[4];
    const float* b2 = (const float*)d_in[5];
    float* out = (float*)d_out;

    int n = in_sizes[0] / 128;
    int E = in_sizes[1] / 2;
    const int* srcA = eidx;
    const int* dstA = eidx + E;

    char* p = (char*)d_ws;
    auto alloc = [&](size_t bytes) {
        char* q = p;
        p += (bytes + 255) & ~(size_t)255;
        return q;
    };
    int*   deg     = (int*)alloc((size_t)n * 4);
    int*   rowptr  = (int*)alloc((size_t)(n + 1) * 4);
    int*   bsum    = (int*)alloc(64 * 4);
    int*   boff    = (int*)alloc(64 * 4);
    float* dinv    = (float*)alloc((size_t)n * 4);
    int*   bcount  = (int*)alloc(NB * 4);
    int*   bbase   = (int*)alloc((NB + 1) * 4);
    int*   gcursor = (int*)alloc(NB * 4);
    int2*  binned  = (int2*)alloc((size_t)E * 8);
    int*   csr     = (int*)alloc((size_t)(E + n) * 4);
    float* h1      = (float*)alloc((size_t)n * 64 * 4);
    float* g1      = (float*)alloc((size_t)n * 64 * 4);
    float* h2      = (float*)alloc((size_t)n * 32 * 4);

    int nb_scan  = (n + BS * 8 - 1) / (BS * 8);   // 49 (<=64 req'd by k_spine)
    int nchunks  = (E + CHUNK - 1) / CHUNK;       // 391
    int nbuckets = (n + BNODES - 1) / BNODES;     // 196 (<= NB)

    k_zero_buckets<<<1, BS, 0, stream>>>(bcount);
    k_count<<<nchunks, BS, 0, stream>>>(dstA, bcount, E);
    k_bucket_scan<<<1, BS, 0, stream>>>(bcount, bbase, gcursor);
    k_scatter<<<nchunks, BS, 0, stream>>>(srcA, dstA, gcursor, binned, E);
    k_b1<<<nbuckets, BS, 0, stream>>>(binned, bbase, deg, n);
    k_block_sums<<<nb_scan, BS, 0, stream>>>(deg, bsum, n);
    k_spine<<<1, 64, 0, stream>>>(bsum, boff, rowptr + n, nb_scan);
    k_scan_final<<<nb_scan, BS, 0, stream>>>(deg, boff, rowptr, dinv, n);
    k_b2<<<nbuckets, BS, 0, stream>>>(binned, bbase, rowptr, csr, n);

    // layer 1: h1 = dinv .* (x @ W1); g1 = dinv .* (A-gather h1)
    k_gemm<128, 64, false><<<(n + 63) / 64, BS, 0, stream>>>(x, W1, nullptr, dinv, h1, n);
    k_agg64<<<((size_t)n * 64 + BS - 1) / BS, BS, 0, stream>>>(h1, csr, rowptr, dinv, g1, n);

    // layer 2: h2 = dinv .* (relu(g1 + b1) @ W2); out = dinv .* (A-gather h2) + b2
    k_gemm<64, 32, true><<<(n + 127) / 128, BS, 0, stream>>>(g1, W2, b1, dinv, h2, n);
    int waves2 = (n + 1) / 2;
    k_agg32<<<((size_t)waves2 * 64 + BS - 1) / BS, BS, 0, stream>>>(h2, csr, rowptr, dinv, b2, out, n);
}

// Round 3
// 316.859 us; speedup vs baseline: 1.5132x; 1.1020x over previous
//
#include <hip/hip_runtime.h>

#define BS 256
#define BSHIFT 9                // 512 nodes per bucket
#define BNODES (1 << BSHIFT)
#define NB 256                  // bucket table size (>= ceil(100000/512)=196)
#define CHUNK 4096              // edges per block for count/scatter (16/thread)

// ---------------- bucketed CSR construction ----------------

__global__ void k_zero_buckets(int* __restrict__ bucketCount) {
    int t = threadIdx.x;
    if (t < NB) bucketCount[t] = 0;
}

__global__ __launch_bounds__(BS) void k_count(const int* __restrict__ dst,
                                              int* __restrict__ bucketCount, int E) {
    __shared__ int h[NB];
    int t = threadIdx.x;
    h[t] = 0;
    __syncthreads();
    int base = blockIdx.x * CHUNK;
#pragma unroll
    for (int j = 0; j < CHUNK / BS; ++j) {
        int e = base + j * BS + t;
        if (e < E) atomicAdd(&h[dst[e] >> BSHIFT], 1);
    }
    __syncthreads();
    if (h[t]) atomicAdd(&bucketCount[t], h[t]);
}

// 1 block, 256 threads: exclusive scan of bucketCount -> bucketBase, gcursor
__global__ void k_bucket_scan(const int* __restrict__ bucketCount,
                              int* __restrict__ bucketBase,
                              int* __restrict__ gcursor) {
    int t = threadIdx.x;
    int v = bucketCount[t];
    int incl = v;
    int lane = t & 63, w = t >> 6;
#pragma unroll
    for (int off = 1; off < 64; off <<= 1) {
        int u = __shfl_up(incl, off);
        if (lane >= off) incl += u;
    }
    __shared__ int ws[4];
    if (lane == 63) ws[w] = incl;
    __syncthreads();
    int woff = 0;
    for (int q = 0; q < w; ++q) woff += ws[q];
    int excl = woff + incl - v;
    bucketBase[t] = excl;
    gcursor[t] = excl;
    if (t == NB - 1) bucketBase[NB] = excl + v;  // == E
}

__global__ __launch_bounds__(BS) void k_scatter(const int* __restrict__ src,
                                                const int* __restrict__ dst,
                                                int* __restrict__ gcursor,
                                                int2* __restrict__ binned, int E) {
    __shared__ int h[NB];
    __shared__ int base[NB];
    int t = threadIdx.x;
    h[t] = 0;
    __syncthreads();
    int cbase = blockIdx.x * CHUNK;
    int sv[CHUNK / BS], dv[CHUNK / BS], rv[CHUNK / BS];
#pragma unroll
    for (int j = 0; j < CHUNK / BS; ++j) {
        int e = cbase + j * BS + t;
        rv[j] = -1;
        if (e < E) {
            sv[j] = src[e];
            dv[j] = dst[e];
            rv[j] = atomicAdd(&h[dv[j] >> BSHIFT], 1);
        }
    }
    __syncthreads();
    base[t] = h[t] ? atomicAdd(&gcursor[t], h[t]) : 0;
    __syncthreads();
#pragma unroll
    for (int j = 0; j < CHUNK / BS; ++j) {
        if (rv[j] >= 0) {
            int b = dv[j] >> BSHIFT;
            binned[base[b] + rv[j]] = make_int2(sv[j], dv[j]);
        }
    }
}

// one block per bucket: per-node degree from binned edges (LDS histogram)
__global__ __launch_bounds__(BS) void k_b1(const int2* __restrict__ binned,
                                           const int* __restrict__ bucketBase,
                                           int* __restrict__ deg, int n) {
    __shared__ int h[BNODES];
    int t = threadIdx.x;
    int node0 = blockIdx.x << BSHIFT;
    int nn = min(BNODES, n - node0);
#pragma unroll
    for (int i = t; i < BNODES; i += BS) h[i] = 0;
    __syncthreads();
    int eb = bucketBase[blockIdx.x], ee = bucketBase[blockIdx.x + 1];
    for (int e = eb + t; e < ee; e += BS) {
        int d = binned[e].y;
        atomicAdd(&h[d - node0], 1);
    }
    __syncthreads();
    for (int i = t; i < nn; i += BS) deg[node0 + i] = h[i] + 1;  // +1 self-loop
}

// ---------------- global scan of deg -> rowptr ----------------

__global__ void k_block_sums(const int* __restrict__ deg, int* __restrict__ bsum, int n) {
    int t = threadIdx.x;
    int base = blockIdx.x * (BS * 8) + t * 8;
    int s = 0;
#pragma unroll
    for (int j = 0; j < 8; ++j) {
        int i = base + j;
        if (i < n) s += deg[i];
    }
#pragma unroll
    for (int off = 32; off > 0; off >>= 1) s += __shfl_down(s, off);
    __shared__ int ws[BS / 64];
    int lane = t & 63, w = t >> 6;
    if (lane == 0) ws[w] = s;
    __syncthreads();
    if (t == 0) {
        int tot = 0;
        for (int q = 0; q < BS / 64; ++q) tot += ws[q];
        bsum[blockIdx.x] = tot;
    }
}

// single wave; nb <= 64 (n=100000 -> nb=49)
__global__ void k_spine(const int* __restrict__ bsum, int* __restrict__ boff,
                        int* __restrict__ total_out, int nb) {
    int t = threadIdx.x;
    int v = (t < nb) ? bsum[t] : 0;
    int incl = v;
#pragma unroll
    for (int off = 1; off < 64; off <<= 1) {
        int u = __shfl_up(incl, off);
        if (t >= off) incl += u;
    }
    if (t < nb) boff[t] = incl - v;  // exclusive
    if (t == 63) *total_out = incl;  // rowptr[n]
}

__global__ void k_scan_final(const int* __restrict__ deg, const int* __restrict__ boff,
                             int* __restrict__ rowptr, float* __restrict__ dinv, int n) {
    int t = threadIdx.x;
    int base = blockIdx.x * (BS * 8) + t * 8;
    int epre[8];
    int run = 0;
#pragma unroll
    for (int j = 0; j < 8; ++j) {
        epre[j] = run;
        int i = base + j;
        if (i < n) run += deg[i];
    }
    int lane = t & 63, w = t >> 6;
    int incl = run;
#pragma unroll
    for (int off = 1; off < 64; off <<= 1) {
        int u = __shfl_up(incl, off);
        if (lane >= off) incl += u;
    }
    __shared__ int ws[BS / 64];
    if (lane == 63) ws[w] = incl;
    __syncthreads();
    int woff = 0;
    for (int q = 0; q < w; ++q) woff += ws[q];
    int texcl = boff[blockIdx.x] + woff + (incl - run);
#pragma unroll
    for (int j = 0; j < 8; ++j) {
        int i = base + j;
        if (i < n) {
            rowptr[i] = texcl + epre[j];
            dinv[i] = rsqrtf((float)deg[i]);
        }
    }
}

// one block per bucket: fill CSR (self-loop first, then binned edges)
__global__ __launch_bounds__(BS) void k_b2(const int2* __restrict__ binned,
                                           const int* __restrict__ bucketBase,
                                           const int* __restrict__ rowptr,
                                           int* __restrict__ csr, int n) {
    __shared__ int rp[BNODES];
    __shared__ int cur[BNODES];
    int t = threadIdx.x;
    int node0 = blockIdx.x << BSHIFT;
    int nn = min(BNODES, n - node0);
#pragma unroll
    for (int i = t; i < BNODES; i += BS) cur[i] = 1;  // slot 0 = self-loop
    for (int i = t; i < nn; i += BS) {
        int r = rowptr[node0 + i];
        rp[i] = r;
        csr[r] = node0 + i;  // self-loop
    }
    __syncthreads();
    int eb = bucketBase[blockIdx.x], ee = bucketBase[blockIdx.x + 1];
    for (int e = eb + t; e < ee; e += BS) {
        int2 p = binned[e];
        int li = p.y - node0;
        int r = atomicAdd(&cur[li], 1);
        csr[rp[li] + r] = p.x;
    }
}

// ---------------- GEMM: H[i][c] = dinv[i] * sum_k act(X[i][k]) * W[k][c] ----------------
// __launch_bounds__(BS, 4): cap VGPR at 128 (r2 showed 256 VGPR + ~30MB scratch
// spill traffic + 9% occupancy). #pragma unroll 4 keeps the live fragment set small.

template <int K, int COLS, bool FUSE>
__global__ __launch_bounds__(BS, 4) void k_gemm(const float* __restrict__ X,
                                                const float* __restrict__ W,
                                                const float* __restrict__ bias,
                                                const float* __restrict__ dscale,
                                                float* __restrict__ H, int n) {
    constexpr int COLS4 = COLS / 4;
    constexpr int TY = BS / COLS4;
    constexpr int ROWS = 4 * TY;
    constexpr int K4 = K / 4;
    __shared__ float sW[K * COLS];
    __shared__ float sX[ROWS * K];
    int tid = threadIdx.x;
    for (int idx = tid; idx < K * COLS4; idx += BS)
        ((float4*)sW)[idx] = ((const float4*)W)[idx];
    int ntiles = (n + ROWS - 1) / ROWS;
    int tx = tid % COLS4, ty = tid / COLS4;
    const float* sWc = &sW[tx * 4];
    for (int tile = blockIdx.x; tile < ntiles; tile += gridDim.x) {
        int row0 = tile * ROWS;
        __syncthreads();
        for (int idx = tid; idx < ROWS * K4; idx += BS) {
            int r = idx / K4, k4 = idx % K4;
            int row = row0 + r;
            float4 v = make_float4(0.f, 0.f, 0.f, 0.f);
            if (row < n) {
                v = ((const float4*)X)[row * K4 + k4];
                if (FUSE) {
                    float4 b = ((const float4*)bias)[k4];
                    v.x = fmaxf(v.x + b.x, 0.f);
                    v.y = fmaxf(v.y + b.y, 0.f);
                    v.z = fmaxf(v.z + b.z, 0.f);
                    v.w = fmaxf(v.w + b.w, 0.f);
                }
            }
            *(float4*)&sX[r * K + ((k4 ^ (r & 7)) << 2)] = v;
        }
        __syncthreads();
        float acc[4][4];
#pragma unroll
        for (int s = 0; s < 4; ++s)
#pragma unroll
            for (int c = 0; c < 4; ++c) acc[s][c] = 0.f;
#pragma unroll 4
        for (int kk = 0; kk < K; kk += 4) {
            int k4 = kk >> 2;
            float4 w0 = *(const float4*)&sWc[(kk + 0) * COLS];
            float4 w1 = *(const float4*)&sWc[(kk + 1) * COLS];
            float4 w2 = *(const float4*)&sWc[(kk + 2) * COLS];
            float4 w3 = *(const float4*)&sWc[(kk + 3) * COLS];
            int xoff = (k4 ^ (ty & 7)) << 2;
#pragma unroll
            for (int s = 0; s < 4; ++s) {
                int r = ty + TY * s;
                float4 xv = *(const float4*)&sX[r * K + xoff];
                acc[s][0] += xv.x * w0.x + xv.y * w1.x + xv.z * w2.x + xv.w * w3.x;
                acc[s][1] += xv.x * w0.y + xv.y * w1.y + xv.z * w2.y + xv.w * w3.y;
                acc[s][2] += xv.x * w0.z + xv.y * w1.z + xv.z * w2.z + xv.w * w3.z;
                acc[s][3] += xv.x * w0.w + xv.y * w1.w + xv.z * w2.w + xv.w * w3.w;
            }
        }
#pragma unroll
        for (int s = 0; s < 4; ++s) {
            int row = row0 + ty + TY * s;
            if (row < n) {
                float dv = dscale[row];
                float4 o = make_float4(acc[s][0] * dv, acc[s][1] * dv,
                                       acc[s][2] * dv, acc[s][3] * dv);
                ((float4*)H)[row * COLS4 + tx] = o;
            }
        }
    }
}

// ---------------- Aggregation (gather-side, no atomics) ----------------

__global__ __launch_bounds__(BS) void k_agg64(const float* __restrict__ h,
                                              const int* __restrict__ csr,
                                              const int* __restrict__ rowptr,
                                              const float* __restrict__ dinv,
                                              float* __restrict__ out, int n) {
    int gw = (blockIdx.x * BS + threadIdx.x) >> 6;
    int lane = threadIdx.x & 63;
    if (gw >= n) return;
    int b = rowptr[gw], e = rowptr[gw + 1];
    float acc = 0.f;
    for (int c = b; c < e; c += 64) {
        int m = e - c;
        if (m > 64) m = 64;
        int sv = (lane < m) ? csr[c + lane] : 0;
        int j = 0;
        for (; j + 3 < m; j += 4) {
            int s0 = __shfl(sv, j), s1 = __shfl(sv, j + 1);
            int s2 = __shfl(sv, j + 2), s3 = __shfl(sv, j + 3);
            float v0 = h[s0 * 64 + lane];
            float v1 = h[s1 * 64 + lane];
            float v2 = h[s2 * 64 + lane];
            float v3 = h[s3 * 64 + lane];
            acc += v0; acc += v1; acc += v2; acc += v3;
        }
        for (; j < m; ++j) {
            int s0 = __shfl(sv, j);
            acc += h[s0 * 64 + lane];
        }
    }
    out[gw * 64 + lane] = acc * dinv[gw];
}

__global__ __launch_bounds__(BS) void k_agg32(const float* __restrict__ h,
                                              const int* __restrict__ csr,
                                              const int* __restrict__ rowptr,
                                              const float* __restrict__ dinv,
                                              const float* __restrict__ bias,
                                              float* __restrict__ out, int n) {
    int wid = (blockIdx.x * BS + threadIdx.x) >> 6;
    int lane = threadIdx.x & 63;
    if (wid * 2 >= n) return;
    int half = lane >> 5, f = lane & 31;
    int node = wid * 2 + half;
    bool valid = node < n;
    int b = 0, e = 0;
    if (valid) { b = rowptr[node]; e = rowptr[node + 1]; }
    float acc = 0.f;
    for (int c = b; c < e; c += 32) {
        int m = e - c;
        if (m > 32) m = 32;
        int sv = (f < m) ? csr[c + f] : 0;
        int j = 0;
        for (; j + 3 < m; j += 4) {
            int s0 = __shfl(sv, j, 32), s1 = __shfl(sv, j + 1, 32);
            int s2 = __shfl(sv, j + 2, 32), s3 = __shfl(sv, j + 3, 32);
            float v0 = h[s0 * 32 + f];
            float v1 = h[s1 * 32 + f];
            float v2 = h[s2 * 32 + f];
            float v3 = h[s3 * 32 + f];
            acc += v0; acc += v1; acc += v2; acc += v3;
        }
        for (; j < m; ++j) {
            int s0 = __shfl(sv, j, 32);
            acc += h[s0 * 32 + f];
        }
    }
    if (valid) out[node * 32 + f] = acc * dinv[node] + bias[f];
}

// ---------------- launch ----------------

extern "C" void kernel_launch(void* const* d_in, const int* in_sizes, int n_in,
                              void* d_out, int out_size, void* d_ws, size_t ws_size,
                              hipStream_t stream) {
    const float* x  = (const float*)d_in[0];
    const int* eidx = (const int*)d_in[1];
    const float* W1 = (const float*)d_in[2];
    const float* b1 = (const float*)d_in[3];
    const float* W2 = (const float*)d_in[4];
    const float* b2 = (const float*)d_in[5];
    float* out = (float*)d_out;

    int n = in_sizes[0] / 128;
    int E = in_sizes[1] / 2;
    const int* srcA = eidx;
    const int* dstA = eidx + E;

    char* p = (char*)d_ws;
    auto alloc = [&](size_t bytes) {
        char* q = p;
        p += (bytes + 255) & ~(size_t)255;
        return q;
    };
    int*   deg     = (int*)alloc((size_t)n * 4);
    int*   rowptr  = (int*)alloc((size_t)(n + 1) * 4);
    int*   bsum    = (int*)alloc(64 * 4);
    int*   boff    = (int*)alloc(64 * 4);
    float* dinv    = (float*)alloc((size_t)n * 4);
    int*   bcount  = (int*)alloc(NB * 4);
    int*   bbase   = (int*)alloc((NB + 1) * 4);
    int*   gcursor = (int*)alloc(NB * 4);
    int2*  binned  = (int2*)alloc((size_t)E * 8);
    int*   csr     = (int*)alloc((size_t)(E + n) * 4);
    float* h1      = (float*)alloc((size_t)n * 64 * 4);
    float* g1      = (float*)alloc((size_t)n * 64 * 4);
    float* h2      = (float*)alloc((size_t)n * 32 * 4);

    int nb_scan  = (n + BS * 8 - 1) / (BS * 8);   // 49 (<=64 req'd by k_spine)
    int nchunks  = (E + CHUNK - 1) / CHUNK;       // 391
    int nbuckets = (n + BNODES - 1) / BNODES;     // 196 (<= NB)

    k_zero_buckets<<<1, BS, 0, stream>>>(bcount);
    k_count<<<nchunks, BS, 0, stream>>>(dstA, bcount, E);
    k_bucket_scan<<<1, BS, 0, stream>>>(bcount, bbase, gcursor);
    k_scatter<<<nchunks, BS, 0, stream>>>(srcA, dstA, gcursor, binned, E);
    k_b1<<<nbuckets, BS, 0, stream>>>(binned, bbase, deg, n);
    k_block_sums<<<nb_scan, BS, 0, stream>>>(deg, bsum, n);
    k_spine<<<1, 64, 0, stream>>>(bsum, boff, rowptr + n, nb_scan);
    k_scan_final<<<nb_scan, BS, 0, stream>>>(deg, boff, rowptr, dinv, n);
    k_b2<<<nbuckets, BS, 0, stream>>>(binned, bbase, rowptr, csr, n);

    // layer 1: h1 = dinv .* (x @ W1); g1 = dinv .* (A-gather h1)
    k_gemm<128, 64, false><<<(n + 63) / 64, BS, 0, stream>>>(x, W1, nullptr, dinv, h1, n);
    k_agg64<<<((size_t)n * 64 + BS - 1) / BS, BS, 0, stream>>>(h1, csr, rowptr, dinv, g1, n);

    // layer 2: h2 = dinv .* (relu(g1 + b1) @ W2); out = dinv .* (A-gather h2) + b2
    k_gemm<64, 32, true><<<(n + 127) / 128, BS, 0, stream>>>(g1, W2, b1, dinv, h2, n);
    int waves2 = (n + 1) / 2;
    k_agg32<<<((size_t)waves2 * 64 + BS - 1) / BS, BS, 0, stream>>>(h2, csr, rowptr, dinv, b2, out, n);
}

// Round 4
// 294.833 us; speedup vs baseline: 1.6262x; 1.0747x over previous
//
#include <hip/hip_runtime.h>
#include <hip/hip_fp16.h>

#define BS 256
#define BSHIFT 9                // 512 nodes per bucket
#define BNODES (1 << BSHIFT)
#define NB 256                  // bucket table size (>= ceil(100000/512)=196)
#define CHUNK 4096              // edges per block for count/scatter (16/thread)

// ---------------- bucketed CSR construction ----------------

__global__ void k_zero_buckets(int* __restrict__ bucketCount) {
    int t = threadIdx.x;
    if (t < NB) bucketCount[t] = 0;
}

__global__ __launch_bounds__(BS) void k_count(const int* __restrict__ dst,
                                              int* __restrict__ bucketCount, int E) {
    __shared__ int h[NB];
    int t = threadIdx.x;
    h[t] = 0;
    __syncthreads();
    int base = blockIdx.x * CHUNK;
#pragma unroll
    for (int j = 0; j < CHUNK / BS; ++j) {
        int e = base + j * BS + t;
        if (e < E) atomicAdd(&h[dst[e] >> BSHIFT], 1);
    }
    __syncthreads();
    if (h[t]) atomicAdd(&bucketCount[t], h[t]);
}

// 1 block, 256 threads: exclusive scan of bucketCount -> bucketBase, gcursor
__global__ void k_bucket_scan(const int* __restrict__ bucketCount,
                              int* __restrict__ bucketBase,
                              int* __restrict__ gcursor) {
    int t = threadIdx.x;
    int v = bucketCount[t];
    int incl = v;
    int lane = t & 63, w = t >> 6;
#pragma unroll
    for (int off = 1; off < 64; off <<= 1) {
        int u = __shfl_up(incl, off);
        if (lane >= off) incl += u;
    }
    __shared__ int ws[4];
    if (lane == 63) ws[w] = incl;
    __syncthreads();
    int woff = 0;
    for (int q = 0; q < w; ++q) woff += ws[q];
    int excl = woff + incl - v;
    bucketBase[t] = excl;
    gcursor[t] = excl;
    if (t == NB - 1) bucketBase[NB] = excl + v;  // == E
}

__global__ __launch_bounds__(BS) void k_scatter(const int* __restrict__ src,
                                                const int* __restrict__ dst,
                                                int* __restrict__ gcursor,
                                                int2* __restrict__ binned, int E) {
    __shared__ int h[NB];
    __shared__ int base[NB];
    int t = threadIdx.x;
    h[t] = 0;
    __syncthreads();
    int cbase = blockIdx.x * CHUNK;
    int sv[CHUNK / BS], dv[CHUNK / BS], rv[CHUNK / BS];
#pragma unroll
    for (int j = 0; j < CHUNK / BS; ++j) {
        int e = cbase + j * BS + t;
        rv[j] = -1;
        if (e < E) {
            sv[j] = src[e];
            dv[j] = dst[e];
            rv[j] = atomicAdd(&h[dv[j] >> BSHIFT], 1);
        }
    }
    __syncthreads();
    base[t] = h[t] ? atomicAdd(&gcursor[t], h[t]) : 0;
    __syncthreads();
#pragma unroll
    for (int j = 0; j < CHUNK / BS; ++j) {
        if (rv[j] >= 0) {
            int b = dv[j] >> BSHIFT;
            binned[base[b] + rv[j]] = make_int2(sv[j], dv[j]);
        }
    }
}

// one block per bucket: per-node degree from binned edges (LDS histogram)
__global__ __launch_bounds__(BS) void k_b1(const int2* __restrict__ binned,
                                           const int* __restrict__ bucketBase,
                                           int* __restrict__ deg, int n) {
    __shared__ int h[BNODES];
    int t = threadIdx.x;
    int node0 = blockIdx.x << BSHIFT;
    int nn = min(BNODES, n - node0);
#pragma unroll
    for (int i = t; i < BNODES; i += BS) h[i] = 0;
    __syncthreads();
    int eb = bucketBase[blockIdx.x], ee = bucketBase[blockIdx.x + 1];
    for (int e = eb + t; e < ee; e += BS) {
        int d = binned[e].y;
        atomicAdd(&h[d - node0], 1);
    }
    __syncthreads();
    for (int i = t; i < nn; i += BS) deg[node0 + i] = h[i] + 1;  // +1 self-loop
}

// ---------------- global scan of deg -> rowptr ----------------

__global__ void k_block_sums(const int* __restrict__ deg, int* __restrict__ bsum, int n) {
    int t = threadIdx.x;
    int base = blockIdx.x * (BS * 8) + t * 8;
    int s = 0;
#pragma unroll
    for (int j = 0; j < 8; ++j) {
        int i = base + j;
        if (i < n) s += deg[i];
    }
#pragma unroll
    for (int off = 32; off > 0; off >>= 1) s += __shfl_down(s, off);
    __shared__ int ws[BS / 64];
    int lane = t & 63, w = t >> 6;
    if (lane == 0) ws[w] = s;
    __syncthreads();
    if (t == 0) {
        int tot = 0;
        for (int q = 0; q < BS / 64; ++q) tot += ws[q];
        bsum[blockIdx.x] = tot;
    }
}

// single wave; nb <= 64 (n=100000 -> nb=49)
__global__ void k_spine(const int* __restrict__ bsum, int* __restrict__ boff,
                        int* __restrict__ total_out, int nb) {
    int t = threadIdx.x;
    int v = (t < nb) ? bsum[t] : 0;
    int incl = v;
#pragma unroll
    for (int off = 1; off < 64; off <<= 1) {
        int u = __shfl_up(incl, off);
        if (t >= off) incl += u;
    }
    if (t < nb) boff[t] = incl - v;  // exclusive
    if (t == 63) *total_out = incl;  // rowptr[n]
}

__global__ void k_scan_final(const int* __restrict__ deg, const int* __restrict__ boff,
                             int* __restrict__ rowptr, float* __restrict__ dinv, int n) {
    int t = threadIdx.x;
    int base = blockIdx.x * (BS * 8) + t * 8;
    int epre[8];
    int run = 0;
#pragma unroll
    for (int j = 0; j < 8; ++j) {
        epre[j] = run;
        int i = base + j;
        if (i < n) run += deg[i];
    }
    int lane = t & 63, w = t >> 6;
    int incl = run;
#pragma unroll
    for (int off = 1; off < 64; off <<= 1) {
        int u = __shfl_up(incl, off);
        if (lane >= off) incl += u;
    }
    __shared__ int ws[BS / 64];
    if (lane == 63) ws[w] = incl;
    __syncthreads();
    int woff = 0;
    for (int q = 0; q < w; ++q) woff += ws[q];
    int texcl = boff[blockIdx.x] + woff + (incl - run);
#pragma unroll
    for (int j = 0; j < 8; ++j) {
        int i = base + j;
        if (i < n) {
            rowptr[i] = texcl + epre[j];
            dinv[i] = rsqrtf((float)deg[i]);
        }
    }
}

// one block per bucket: fill CSR (self-loop first, then binned edges)
__global__ __launch_bounds__(BS) void k_b2(const int2* __restrict__ binned,
                                           const int* __restrict__ bucketBase,
                                           const int* __restrict__ rowptr,
                                           int* __restrict__ csr, int n) {
    __shared__ int rp[BNODES];
    __shared__ int cur[BNODES];
    int t = threadIdx.x;
    int node0 = blockIdx.x << BSHIFT;
    int nn = min(BNODES, n - node0);
#pragma unroll
    for (int i = t; i < BNODES; i += BS) cur[i] = 1;  // slot 0 = self-loop
    for (int i = t; i < nn; i += BS) {
        int r = rowptr[node0 + i];
        rp[i] = r;
        csr[r] = node0 + i;  // self-loop
    }
    __syncthreads();
    int eb = bucketBase[blockIdx.x], ee = bucketBase[blockIdx.x + 1];
    for (int e = eb + t; e < ee; e += BS) {
        int2 p = binned[e];
        int li = p.y - node0;
        int r = atomicAdd(&cur[li], 1);
        csr[rp[li] + r] = p.x;
    }
}

// ---------------- GEMM: H[i][c] = dinv[i] * sum_k act(X[i][k]) * W[k][c] ----------------
// IN_HALF/OUT_HALF select fp16 I/O (fabric-bytes reduction for the gather kernels);
// staging, math, and accumulate stay fp32.

template <int K, int COLS, bool FUSE, bool IN_HALF, bool OUT_HALF>
__global__ __launch_bounds__(BS, 4) void k_gemm(const void* __restrict__ Xv,
                                                const float* __restrict__ W,
                                                const float* __restrict__ bias,
                                                const float* __restrict__ dscale,
                                                void* __restrict__ Hv, int n) {
    constexpr int COLS4 = COLS / 4;
    constexpr int TY = BS / COLS4;
    constexpr int ROWS = 4 * TY;
    constexpr int K4 = K / 4;
    __shared__ float sW[K * COLS];
    __shared__ float sX[ROWS * K];
    int tid = threadIdx.x;
    for (int idx = tid; idx < K * COLS4; idx += BS)
        ((float4*)sW)[idx] = ((const float4*)W)[idx];
    int ntiles = (n + ROWS - 1) / ROWS;
    int tx = tid % COLS4, ty = tid / COLS4;
    const float* sWc = &sW[tx * 4];
    for (int tile = blockIdx.x; tile < ntiles; tile += gridDim.x) {
        int row0 = tile * ROWS;
        __syncthreads();
        for (int idx = tid; idx < ROWS * K4; idx += BS) {
            int r = idx / K4, k4 = idx % K4;
            int row = row0 + r;
            float4 v = make_float4(0.f, 0.f, 0.f, 0.f);
            if (row < n) {
                if (IN_HALF) {
                    const __half2* X2 = ((const __half2*)Xv) + (size_t)row * (K / 2) + k4 * 2;
                    float2 a = __half22float2(X2[0]);
                    float2 b = __half22float2(X2[1]);
                    v = make_float4(a.x, a.y, b.x, b.y);
                } else {
                    v = ((const float4*)Xv)[(size_t)row * K4 + k4];
                }
                if (FUSE) {
                    float4 b = ((const float4*)bias)[k4];
                    v.x = fmaxf(v.x + b.x, 0.f);
                    v.y = fmaxf(v.y + b.y, 0.f);
                    v.z = fmaxf(v.z + b.z, 0.f);
                    v.w = fmaxf(v.w + b.w, 0.f);
                }
            }
            *(float4*)&sX[r * K + ((k4 ^ (r & 7)) << 2)] = v;
        }
        __syncthreads();
        float acc[4][4];
#pragma unroll
        for (int s = 0; s < 4; ++s)
#pragma unroll
            for (int c = 0; c < 4; ++c) acc[s][c] = 0.f;
#pragma unroll 4
        for (int kk = 0; kk < K; kk += 4) {
            int k4 = kk >> 2;
            float4 w0 = *(const float4*)&sWc[(kk + 0) * COLS];
            float4 w1 = *(const float4*)&sWc[(kk + 1) * COLS];
            float4 w2 = *(const float4*)&sWc[(kk + 2) * COLS];
            float4 w3 = *(const float4*)&sWc[(kk + 3) * COLS];
            int xoff = (k4 ^ (ty & 7)) << 2;
#pragma unroll
            for (int s = 0; s < 4; ++s) {
                int r = ty + TY * s;
                float4 xv = *(const float4*)&sX[r * K + xoff];
                acc[s][0] += xv.x * w0.x + xv.y * w1.x + xv.z * w2.x + xv.w * w3.x;
                acc[s][1] += xv.x * w0.y + xv.y * w1.y + xv.z * w2.y + xv.w * w3.y;
                acc[s][2] += xv.x * w0.z + xv.y * w1.z + xv.z * w2.z + xv.w * w3.z;
                acc[s][3] += xv.x * w0.w + xv.y * w1.w + xv.z * w2.w + xv.w * w3.w;
            }
        }
#pragma unroll
        for (int s = 0; s < 4; ++s) {
            int row = row0 + ty + TY * s;
            if (row < n) {
                float dv = dscale[row];
                float4 o = make_float4(acc[s][0] * dv, acc[s][1] * dv,
                                       acc[s][2] * dv, acc[s][3] * dv);
                if (OUT_HALF) {
                    float2 pk;
                    ((__half2*)&pk)[0] = __floats2half2_rn(o.x, o.y);
                    ((__half2*)&pk)[1] = __floats2half2_rn(o.z, o.w);
                    ((float2*)Hv)[(size_t)row * COLS4 + tx] = pk;
                } else {
                    ((float4*)Hv)[(size_t)row * COLS4 + tx] = o;
                }
            }
        }
    }
}

// ---------------- Aggregation (gather-side, no atomics; h in fp16) ----------------
// h is pre-scaled by dinv[src]; out[i] = dinv[i] * sum_{s in row i} h[s][:]

__global__ __launch_bounds__(BS) void k_agg64(const __half* __restrict__ h,
                                              const int* __restrict__ csr,
                                              const int* __restrict__ rowptr,
                                              const float* __restrict__ dinv,
                                              __half* __restrict__ out, int n) {
    int gw = (blockIdx.x * BS + threadIdx.x) >> 6;
    int lane = threadIdx.x & 63;
    if (gw >= n) return;
    int b = rowptr[gw], e = rowptr[gw + 1];
    float acc = 0.f;
    for (int c = b; c < e; c += 64) {
        int m = e - c;
        if (m > 64) m = 64;
        int sv = (lane < m) ? csr[c + lane] : 0;
        int j = 0;
        for (; j + 3 < m; j += 4) {
            int s0 = __shfl(sv, j), s1 = __shfl(sv, j + 1);
            int s2 = __shfl(sv, j + 2), s3 = __shfl(sv, j + 3);
            float v0 = __half2float(h[(size_t)s0 * 64 + lane]);
            float v1 = __half2float(h[(size_t)s1 * 64 + lane]);
            float v2 = __half2float(h[(size_t)s2 * 64 + lane]);
            float v3 = __half2float(h[(size_t)s3 * 64 + lane]);
            acc += v0; acc += v1; acc += v2; acc += v3;
        }
        for (; j < m; ++j) {
            int s0 = __shfl(sv, j);
            acc += __half2float(h[(size_t)s0 * 64 + lane]);
        }
    }
    out[(size_t)gw * 64 + lane] = __float2half_rn(acc * dinv[gw]);
}

// 32 features: two nodes per wave (half-wave each); adds final bias b; fp32 out.
__global__ __launch_bounds__(BS) void k_agg32(const __half* __restrict__ h,
                                              const int* __restrict__ csr,
                                              const int* __restrict__ rowptr,
                                              const float* __restrict__ dinv,
                                              const float* __restrict__ bias,
                                              float* __restrict__ out, int n) {
    int wid = (blockIdx.x * BS + threadIdx.x) >> 6;
    int lane = threadIdx.x & 63;
    if (wid * 2 >= n) return;
    int half = lane >> 5, f = lane & 31;
    int node = wid * 2 + half;
    bool valid = node < n;
    int b = 0, e = 0;
    if (valid) { b = rowptr[node]; e = rowptr[node + 1]; }
    float acc = 0.f;
    for (int c = b; c < e; c += 32) {
        int m = e - c;
        if (m > 32) m = 32;
        int sv = (f < m) ? csr[c + f] : 0;
        int j = 0;
        for (; j + 3 < m; j += 4) {
            int s0 = __shfl(sv, j, 32), s1 = __shfl(sv, j + 1, 32);
            int s2 = __shfl(sv, j + 2, 32), s3 = __shfl(sv, j + 3, 32);
            float v0 = __half2float(h[(size_t)s0 * 32 + f]);
            float v1 = __half2float(h[(size_t)s1 * 32 + f]);
            float v2 = __half2float(h[(size_t)s2 * 32 + f]);
            float v3 = __half2float(h[(size_t)s3 * 32 + f]);
            acc += v0; acc += v1; acc += v2; acc += v3;
        }
        for (; j < m; ++j) {
            int s0 = __shfl(sv, j, 32);
            acc += __half2float(h[(size_t)s0 * 32 + f]);
        }
    }
    if (valid) out[(size_t)node * 32 + f] = acc * dinv[node] + bias[f];
}

// ---------------- launch ----------------

extern "C" void kernel_launch(void* const* d_in, const int* in_sizes, int n_in,
                              void* d_out, int out_size, void* d_ws, size_t ws_size,
                              hipStream_t stream) {
    const float* x  = (const float*)d_in[0];
    const int* eidx = (const int*)d_in[1];
    const float* W1 = (const float*)d_in[2];
    const float* b1 = (const float*)d_in[3];
    const float* W2 = (const float*)d_in[4];
    const float* b2 = (const float*)d_in[5];
    float* out = (float*)d_out;

    int n = in_sizes[0] / 128;
    int E = in_sizes[1] / 2;
    const int* srcA = eidx;
    const int* dstA = eidx + E;

    char* p = (char*)d_ws;
    auto alloc = [&](size_t bytes) {
        char* q = p;
        p += (bytes + 255) & ~(size_t)255;
        return q;
    };
    int*    deg     = (int*)alloc((size_t)n * 4);
    int*    rowptr  = (int*)alloc((size_t)(n + 1) * 4);
    int*    bsum    = (int*)alloc(64 * 4);
    int*    boff    = (int*)alloc(64 * 4);
    float*  dinv    = (float*)alloc((size_t)n * 4);
    int*    bcount  = (int*)alloc(NB * 4);
    int*    bbase   = (int*)alloc((NB + 1) * 4);
    int*    gcursor = (int*)alloc(NB * 4);
    int2*   binned  = (int2*)alloc((size_t)E * 8);
    int*    csr     = (int*)alloc((size_t)(E + n) * 4);
    __half* h1      = (__half*)alloc((size_t)n * 64 * 2);
    __half* g1      = (__half*)alloc((size_t)n * 64 * 2);
    __half* h2      = (__half*)alloc((size_t)n * 32 * 2);

    int nb_scan  = (n + BS * 8 - 1) / (BS * 8);   // 49 (<=64 req'd by k_spine)
    int nchunks  = (E + CHUNK - 1) / CHUNK;       // 391
    int nbuckets = (n + BNODES - 1) / BNODES;     // 196 (<= NB)

    k_zero_buckets<<<1, BS, 0, stream>>>(bcount);
    k_count<<<nchunks, BS, 0, stream>>>(dstA, bcount, E);
    k_bucket_scan<<<1, BS, 0, stream>>>(bcount, bbase, gcursor);
    k_scatter<<<nchunks, BS, 0, stream>>>(srcA, dstA, gcursor, binned, E);
    k_b1<<<nbuckets, BS, 0, stream>>>(binned, bbase, deg, n);
    k_block_sums<<<nb_scan, BS, 0, stream>>>(deg, bsum, n);
    k_spine<<<1, 64, 0, stream>>>(bsum, boff, rowptr + n, nb_scan);
    k_scan_final<<<nb_scan, BS, 0, stream>>>(deg, boff, rowptr, dinv, n);
    k_b2<<<nbuckets, BS, 0, stream>>>(binned, bbase, rowptr, csr, n);

    // layer 1: h1 = dinv .* (x @ W1)  [fp16]; g1 = dinv .* (A-gather h1)  [fp16]
    k_gemm<128, 64, false, false, true><<<(n + 63) / 64, BS, 0, stream>>>(x, W1, nullptr, dinv, h1, n);
    k_agg64<<<((size_t)n * 64 + BS - 1) / BS, BS, 0, stream>>>(h1, csr, rowptr, dinv, g1, n);

    // layer 2: h2 = dinv .* (relu(g1 + b1) @ W2)  [fp16]; out = dinv .* (A-gather h2) + b2  [fp32]
    k_gemm<64, 32, true, true, true><<<(n + 127) / 128, BS, 0, stream>>>(g1, W2, b1, dinv, h2, n);
    int waves2 = (n + 1) / 2;
    k_agg32<<<((size_t)waves2 * 64 + BS - 1) / BS, BS, 0, stream>>>(h2, csr, rowptr, dinv, b2, out, n);
}

// Round 5
// 282.768 us; speedup vs baseline: 1.6956x; 1.0427x over previous
//
#include <hip/hip_runtime.h>
#include <hip/hip_fp16.h>

#define BS 256
#define BSHIFT 9                // 512 nodes per bucket
#define BNODES (1 << BSHIFT)
#define NB 256                  // bucket table size (>= ceil(100000/512)=196)
#define CHUNK 4096              // edges per block for count/scatter (16/thread)

typedef _Float16 f16x8 __attribute__((ext_vector_type(8)));
typedef float f32x4 __attribute__((ext_vector_type(4)));

// ---------------- bucketed CSR construction ----------------

__global__ void k_zero_buckets(int* __restrict__ bucketCount) {
    int t = threadIdx.x;
    if (t < NB) bucketCount[t] = 0;
}

__global__ __launch_bounds__(BS) void k_count(const int* __restrict__ dst,
                                              int* __restrict__ bucketCount, int E) {
    __shared__ int h[NB];
    int t = threadIdx.x;
    h[t] = 0;
    __syncthreads();
    int base = blockIdx.x * CHUNK;
#pragma unroll
    for (int j = 0; j < CHUNK / BS; ++j) {
        int e = base + j * BS + t;
        if (e < E) atomicAdd(&h[dst[e] >> BSHIFT], 1);
    }
    __syncthreads();
    if (h[t]) atomicAdd(&bucketCount[t], h[t]);
}

// 1 block, 256 threads: exclusive scan of bucketCount -> bucketBase, gcursor
__global__ void k_bucket_scan(const int* __restrict__ bucketCount,
                              int* __restrict__ bucketBase,
                              int* __restrict__ gcursor) {
    int t = threadIdx.x;
    int v = bucketCount[t];
    int incl = v;
    int lane = t & 63, w = t >> 6;
#pragma unroll
    for (int off = 1; off < 64; off <<= 1) {
        int u = __shfl_up(incl, off);
        if (lane >= off) incl += u;
    }
    __shared__ int ws[4];
    if (lane == 63) ws[w] = incl;
    __syncthreads();
    int woff = 0;
    for (int q = 0; q < w; ++q) woff += ws[q];
    int excl = woff + incl - v;
    bucketBase[t] = excl;
    gcursor[t] = excl;
    if (t == NB - 1) bucketBase[NB] = excl + v;  // == E
}

__global__ __launch_bounds__(BS) void k_scatter(const int* __restrict__ src,
                                                const int* __restrict__ dst,
                                                int* __restrict__ gcursor,
                                                int2* __restrict__ binned, int E) {
    __shared__ int h[NB];
    __shared__ int base[NB];
    int t = threadIdx.x;
    h[t] = 0;
    __syncthreads();
    int cbase = blockIdx.x * CHUNK;
    int sv[CHUNK / BS], dv[CHUNK / BS], rv[CHUNK / BS];
#pragma unroll
    for (int j = 0; j < CHUNK / BS; ++j) {
        int e = cbase + j * BS + t;
        rv[j] = -1;
        if (e < E) {
            sv[j] = src[e];
            dv[j] = dst[e];
            rv[j] = atomicAdd(&h[dv[j] >> BSHIFT], 1);
        }
    }
    __syncthreads();
    base[t] = h[t] ? atomicAdd(&gcursor[t], h[t]) : 0;
    __syncthreads();
#pragma unroll
    for (int j = 0; j < CHUNK / BS; ++j) {
        if (rv[j] >= 0) {
            int b = dv[j] >> BSHIFT;
            binned[base[b] + rv[j]] = make_int2(sv[j], dv[j]);
        }
    }
}

// one block per bucket: per-node degree from binned edges (LDS histogram)
__global__ __launch_bounds__(BS) void k_b1(const int2* __restrict__ binned,
                                           const int* __restrict__ bucketBase,
                                           int* __restrict__ deg, int n) {
    __shared__ int h[BNODES];
    int t = threadIdx.x;
    int node0 = blockIdx.x << BSHIFT;
    int nn = min(BNODES, n - node0);
#pragma unroll
    for (int i = t; i < BNODES; i += BS) h[i] = 0;
    __syncthreads();
    int eb = bucketBase[blockIdx.x], ee = bucketBase[blockIdx.x + 1];
    for (int e = eb + t; e < ee; e += BS) {
        int d = binned[e].y;
        atomicAdd(&h[d - node0], 1);
    }
    __syncthreads();
    for (int i = t; i < nn; i += BS) deg[node0 + i] = h[i] + 1;  // +1 self-loop
}

// ---------------- global scan of deg -> rowptr ----------------

__global__ void k_block_sums(const int* __restrict__ deg, int* __restrict__ bsum, int n) {
    int t = threadIdx.x;
    int base = blockIdx.x * (BS * 8) + t * 8;
    int s = 0;
#pragma unroll
    for (int j = 0; j < 8; ++j) {
        int i = base + j;
        if (i < n) s += deg[i];
    }
#pragma unroll
    for (int off = 32; off > 0; off >>= 1) s += __shfl_down(s, off);
    __shared__ int ws[BS / 64];
    int lane = t & 63, w = t >> 6;
    if (lane == 0) ws[w] = s;
    __syncthreads();
    if (t == 0) {
        int tot = 0;
        for (int q = 0; q < BS / 64; ++q) tot += ws[q];
        bsum[blockIdx.x] = tot;
    }
}

// single wave; nb <= 64 (n=100000 -> nb=49)
__global__ void k_spine(const int* __restrict__ bsum, int* __restrict__ boff,
                        int* __restrict__ total_out, int nb) {
    int t = threadIdx.x;
    int v = (t < nb) ? bsum[t] : 0;
    int incl = v;
#pragma unroll
    for (int off = 1; off < 64; off <<= 1) {
        int u = __shfl_up(incl, off);
        if (t >= off) incl += u;
    }
    if (t < nb) boff[t] = incl - v;  // exclusive
    if (t == 63) *total_out = incl;  // rowptr[n]
}

__global__ void k_scan_final(const int* __restrict__ deg, const int* __restrict__ boff,
                             int* __restrict__ rowptr, float* __restrict__ dinv, int n) {
    int t = threadIdx.x;
    int base = blockIdx.x * (BS * 8) + t * 8;
    int epre[8];
    int run = 0;
#pragma unroll
    for (int j = 0; j < 8; ++j) {
        epre[j] = run;
        int i = base + j;
        if (i < n) run += deg[i];
    }
    int lane = t & 63, w = t >> 6;
    int incl = run;
#pragma unroll
    for (int off = 1; off < 64; off <<= 1) {
        int u = __shfl_up(incl, off);
        if (lane >= off) incl += u;
    }
    __shared__ int ws[BS / 64];
    if (lane == 63) ws[w] = incl;
    __syncthreads();
    int woff = 0;
    for (int q = 0; q < w; ++q) woff += ws[q];
    int texcl = boff[blockIdx.x] + woff + (incl - run);
#pragma unroll
    for (int j = 0; j < 8; ++j) {
        int i = base + j;
        if (i < n) {
            rowptr[i] = texcl + epre[j];
            dinv[i] = rsqrtf((float)deg[i]);
        }
    }
}

// one block per bucket: fill CSR (self-loop first, then binned edges)
__global__ __launch_bounds__(BS) void k_b2(const int2* __restrict__ binned,
                                           const int* __restrict__ bucketBase,
                                           const int* __restrict__ rowptr,
                                           int* __restrict__ csr, int n) {
    __shared__ int rp[BNODES];
    __shared__ int cur[BNODES];
    int t = threadIdx.x;
    int node0 = blockIdx.x << BSHIFT;
    int nn = min(BNODES, n - node0);
#pragma unroll
    for (int i = t; i < BNODES; i += BS) cur[i] = 1;  // slot 0 = self-loop
    for (int i = t; i < nn; i += BS) {
        int r = rowptr[node0 + i];
        rp[i] = r;
        csr[r] = node0 + i;  // self-loop
    }
    __syncthreads();
    int eb = bucketBase[blockIdx.x], ee = bucketBase[blockIdx.x + 1];
    for (int e = eb + t; e < ee; e += BS) {
        int2 p = binned[e];
        int li = p.y - node0;
        int r = atomicAdd(&cur[li], 1);
        csr[rp[li] + r] = p.x;
    }
}

// ---------------- MFMA GEMM: H[i][c] = fp16(dinv[i] * sum_k act(X[i][k]) * W[k][c]) ----
// fp16 inputs to mfma_f32_16x16x32_f16, fp32 accumulate. Block = 128 rows, 4 waves;
// wave w computes rows w*32..w*32+31 x all COLS. A and W^T staged in LDS fp16 with
// 16B-chunk XOR swizzle (row stride is bank-aligned; unswizzled frag reads would be
// 16-way bank conflicts). Verified layouts (m89/m120): A[m=lane&15][k=quad*8+j],
// B^T[n=lane&15][k=quad*8+j], D row=quad*4+reg col=lane&15.

template <int K, int COLS, bool FUSE, bool IN_HALF>
__global__ __launch_bounds__(BS, 3) void k_mgemm(const void* __restrict__ Xv,
                                                 const float* __restrict__ W,
                                                 const float* __restrict__ bias,
                                                 const float* __restrict__ dscale,
                                                 __half* __restrict__ H, int n) {
    constexpr int KC = K / 8;                         // 16B chunks per row
    constexpr int SWZ = (KC - 1) < 15 ? (KC - 1) : 15;  // 15 (K=128) / 7 (K=64)
    constexpr int NT = COLS / 16;                     // n-tiles per wave
    __shared__ __align__(16) _Float16 sA[128 * K];
    __shared__ __align__(16) _Float16 sB[COLS * K];
    int tid = threadIdx.x;
    int row0 = blockIdx.x * 128;

    // stage W^T (fp32 global, strided reads; W is L2-resident)
    for (int idx = tid; idx < COLS * KC; idx += BS) {
        int c = idx / KC, k8 = idx % KC;
        f16x8 v;
#pragma unroll
        for (int j = 0; j < 8; ++j) v[j] = (_Float16)W[(k8 * 8 + j) * COLS + c];
        *(f16x8*)&sB[c * K + ((k8 ^ (c & SWZ)) * 8)] = v;
    }
    // stage X tile (convert to fp16; FUSE applies relu(x+bias))
    for (int idx = tid; idx < 128 * KC; idx += BS) {
        int r = idx / KC, k8 = idx % KC;
        int row = row0 + r;
        f16x8 v = {};
        if (row < n) {
            float f[8];
            if (IN_HALF) {
                const __half2* xp = (const __half2*)Xv + (size_t)row * (K / 2) + k8 * 4;
#pragma unroll
                for (int t2 = 0; t2 < 4; ++t2) {
                    float2 p = __half22float2(xp[t2]);
                    f[2 * t2] = p.x; f[2 * t2 + 1] = p.y;
                }
            } else {
                const float4* xp = (const float4*)Xv + (size_t)row * (K / 4) + k8 * 2;
                float4 a = xp[0], b = xp[1];
                f[0] = a.x; f[1] = a.y; f[2] = a.z; f[3] = a.w;
                f[4] = b.x; f[5] = b.y; f[6] = b.z; f[7] = b.w;
            }
            if (FUSE) {
                const float4* bp = (const float4*)bias + k8 * 2;
                float4 a = bp[0], b = bp[1];
                float bb[8] = {a.x, a.y, a.z, a.w, b.x, b.y, b.z, b.w};
#pragma unroll
                for (int t2 = 0; t2 < 8; ++t2) f[t2] = fmaxf(f[t2] + bb[t2], 0.f);
            }
#pragma unroll
            for (int t2 = 0; t2 < 8; ++t2) v[t2] = (_Float16)f[t2];
        }
        *(f16x8*)&sA[r * K + ((k8 ^ (r & SWZ)) * 8)] = v;
    }
    __syncthreads();

    int w = tid >> 6, lane = tid & 63;
    int lm = lane & 15, q = lane >> 4;
    f32x4 acc[2][NT];
#pragma unroll
    for (int tm = 0; tm < 2; ++tm)
#pragma unroll
        for (int tn = 0; tn < NT; ++tn) acc[tm][tn] = (f32x4){0.f, 0.f, 0.f, 0.f};

#pragma unroll
    for (int kc8 = 0; kc8 < KC; kc8 += 4) {  // 32-k step
        f16x8 af[2], bf[NT];
#pragma unroll
        for (int tm = 0; tm < 2; ++tm) {
            int r = w * 32 + tm * 16 + lm;
            af[tm] = *(const f16x8*)&sA[r * K + (((kc8 + q) ^ (r & SWZ)) * 8)];
        }
#pragma unroll
        for (int tn = 0; tn < NT; ++tn) {
            int c = tn * 16 + lm;
            bf[tn] = *(const f16x8*)&sB[c * K + (((kc8 + q) ^ (c & SWZ)) * 8)];
        }
#pragma unroll
        for (int tm = 0; tm < 2; ++tm)
#pragma unroll
            for (int tn = 0; tn < NT; ++tn)
                acc[tm][tn] = __builtin_amdgcn_mfma_f32_16x16x32_f16(af[tm], bf[tn],
                                                                     acc[tm][tn], 0, 0, 0);
    }

#pragma unroll
    for (int tm = 0; tm < 2; ++tm) {
#pragma unroll
        for (int r = 0; r < 4; ++r) {
            int row = row0 + w * 32 + tm * 16 + q * 4 + r;
            if (row < n) {
                float dv = dscale[row];
#pragma unroll
                for (int tn = 0; tn < NT; ++tn) {
                    int col = tn * 16 + lm;
                    H[(size_t)row * COLS + col] = __float2half_rn(acc[tm][tn][r] * dv);
                }
            }
        }
    }
}

// ---------------- Aggregation (gather-side, no atomics; h in fp16) ----------------
// h is pre-scaled by dinv[src]; out[i] = dinv[i] * sum_{s in row i} h[s][:]
// agg64: one wave per node, 4 edges/iter (16 lanes/edge x 8B half2x2 loads).

__global__ __launch_bounds__(BS) void k_agg64(const __half* __restrict__ h,
                                              const int* __restrict__ csr,
                                              const int* __restrict__ rowptr,
                                              const float* __restrict__ dinv,
                                              __half* __restrict__ out, int n) {
    int gw = (blockIdx.x * BS + threadIdx.x) >> 6;
    int lane = threadIdx.x & 63;
    if (gw >= n) return;
    int slot = lane >> 4, fq = lane & 15;  // features fq*4..fq*4+3, edge slot 0..3
    int b = rowptr[gw], e = rowptr[gw + 1];
    float a0 = 0.f, a1 = 0.f, a2 = 0.f, a3 = 0.f;
    for (int c = b; c < e; c += 64) {
        int m = e - c;
        if (m > 64) m = 64;
        int sv = (lane < m) ? csr[c + lane] : 0;
        for (int j = 0; j < m; j += 4) {
            int js = j + slot;
            int s = __shfl(sv, js < m ? js : 0);
            if (js < m) {
                float2 raw = *(const float2*)(h + (size_t)s * 64 + fq * 4);
                __half2 h0 = ((const __half2*)&raw)[0], h1 = ((const __half2*)&raw)[1];
                float2 f0 = __half22float2(h0), f1 = __half22float2(h1);
                a0 += f0.x; a1 += f0.y; a2 += f1.x; a3 += f1.y;
            }
        }
    }
    a0 += __shfl_down(a0, 32); a1 += __shfl_down(a1, 32);
    a2 += __shfl_down(a2, 32); a3 += __shfl_down(a3, 32);
    a0 += __shfl_down(a0, 16); a1 += __shfl_down(a1, 16);
    a2 += __shfl_down(a2, 16); a3 += __shfl_down(a3, 16);
    if (lane < 16) {
        float dv = dinv[gw];
        union { __half2 h2[2]; float2 f2; } pk;
        pk.h2[0] = __floats2half2_rn(a0 * dv, a1 * dv);
        pk.h2[1] = __floats2half2_rn(a2 * dv, a3 * dv);
        *(float2*)(out + (size_t)gw * 64 + lane * 4) = pk.f2;
    }
}

// agg32: one wave per node, 8 edges/iter (8 lanes/edge x 8B); fp32 out + bias.
__global__ __launch_bounds__(BS) void k_agg32(const __half* __restrict__ h,
                                              const int* __restrict__ csr,
                                              const int* __restrict__ rowptr,
                                              const float* __restrict__ dinv,
                                              const float* __restrict__ bias,
                                              float* __restrict__ out, int n) {
    int gw = (blockIdx.x * BS + threadIdx.x) >> 6;
    int lane = threadIdx.x & 63;
    if (gw >= n) return;
    int slot = lane >> 3, fq = lane & 7;  // features fq*4..fq*4+3, edge slot 0..7
    int b = rowptr[gw], e = rowptr[gw + 1];
    float a0 = 0.f, a1 = 0.f, a2 = 0.f, a3 = 0.f;
    for (int c = b; c < e; c += 64) {
        int m = e - c;
        if (m > 64) m = 64;
        int sv = (lane < m) ? csr[c + lane] : 0;
        for (int j = 0; j < m; j += 8) {
            int js = j + slot;
            int s = __shfl(sv, js < m ? js : 0);
            if (js < m) {
                float2 raw = *(const float2*)(h + (size_t)s * 32 + fq * 4);
                __half2 h0 = ((const __half2*)&raw)[0], h1 = ((const __half2*)&raw)[1];
                float2 f0 = __half22float2(h0), f1 = __half22float2(h1);
                a0 += f0.x; a1 += f0.y; a2 += f1.x; a3 += f1.y;
            }
        }
    }
    a0 += __shfl_down(a0, 32); a1 += __shfl_down(a1, 32);
    a2 += __shfl_down(a2, 32); a3 += __shfl_down(a3, 32);
    a0 += __shfl_down(a0, 16); a1 += __shfl_down(a1, 16);
    a2 += __shfl_down(a2, 16); a3 += __shfl_down(a3, 16);
    a0 += __shfl_down(a0, 8);  a1 += __shfl_down(a1, 8);
    a2 += __shfl_down(a2, 8);  a3 += __shfl_down(a3, 8);
    if (lane < 8) {
        float dv = dinv[gw];
        float4 bv = ((const float4*)bias)[lane];
        float4 o = make_float4(a0 * dv + bv.x, a1 * dv + bv.y,
                               a2 * dv + bv.z, a3 * dv + bv.w);
        ((float4*)(out + (size_t)gw * 32))[lane] = o;
    }
}

// ---------------- launch ----------------

extern "C" void kernel_launch(void* const* d_in, const int* in_sizes, int n_in,
                              void* d_out, int out_size, void* d_ws, size_t ws_size,
                              hipStream_t stream) {
    const float* x  = (const float*)d_in[0];
    const int* eidx = (const int*)d_in[1];
    const float* W1 = (const float*)d_in[2];
    const float* b1 = (const float*)d_in[3];
    const float* W2 = (const float*)d_in[4];
    const float* b2 = (const float*)d_in[5];
    float* out = (float*)d_out;

    int n = in_sizes[0] / 128;
    int E = in_sizes[1] / 2;
    const int* srcA = eidx;
    const int* dstA = eidx + E;

    char* p = (char*)d_ws;
    auto alloc = [&](size_t bytes) {
        char* q = p;
        p += (bytes + 255) & ~(size_t)255;
        return q;
    };
    int*    deg     = (int*)alloc((size_t)n * 4);
    int*    rowptr  = (int*)alloc((size_t)(n + 1) * 4);
    int*    bsum    = (int*)alloc(64 * 4);
    int*    boff    = (int*)alloc(64 * 4);
    float*  dinv    = (float*)alloc((size_t)n * 4);
    int*    bcount  = (int*)alloc(NB * 4);
    int*    bbase   = (int*)alloc((NB + 1) * 4);
    int*    gcursor = (int*)alloc(NB * 4);
    int2*   binned  = (int2*)alloc((size_t)E * 8);
    int*    csr     = (int*)alloc((size_t)(E + n) * 4);
    __half* h1      = (__half*)alloc((size_t)n * 64 * 2);
    __half* g1      = (__half*)alloc((size_t)n * 64 * 2);
    __half* h2      = (__half*)alloc((size_t)n * 32 * 2);

    int nb_scan  = (n + BS * 8 - 1) / (BS * 8);   // 49 (<=64 req'd by k_spine)
    int nchunks  = (E + CHUNK - 1) / CHUNK;       // 391
    int nbuckets = (n + BNODES - 1) / BNODES;     // 196 (<= NB)
    int nblk     = (n + 127) / 128;               // 782 MFMA-GEMM tiles
    int aggblk   = (int)(((size_t)n * 64 + BS - 1) / BS);

    k_zero_buckets<<<1, BS, 0, stream>>>(bcount);
    k_count<<<nchunks, BS, 0, stream>>>(dstA, bcount, E);
    k_bucket_scan<<<1, BS, 0, stream>>>(bcount, bbase, gcursor);
    k_scatter<<<nchunks, BS, 0, stream>>>(srcA, dstA, gcursor, binned, E);
    k_b1<<<nbuckets, BS, 0, stream>>>(binned, bbase, deg, n);
    k_block_sums<<<nb_scan, BS, 0, stream>>>(deg, bsum, n);
    k_spine<<<1, 64, 0, stream>>>(bsum, boff, rowptr + n, nb_scan);
    k_scan_final<<<nb_scan, BS, 0, stream>>>(deg, boff, rowptr, dinv, n);
    k_b2<<<nbuckets, BS, 0, stream>>>(binned, bbase, rowptr, csr, n);

    // layer 1: h1 = dinv .* (x @ W1)  [fp16 MFMA]; g1 = dinv .* (A-gather h1)
    k_mgemm<128, 64, false, false><<<nblk, BS, 0, stream>>>(x, W1, nullptr, dinv, h1, n);
    k_agg64<<<aggblk, BS, 0, stream>>>(h1, csr, rowptr, dinv, g1, n);

    // layer 2: h2 = dinv .* (relu(g1 + b1) @ W2)  [fp16 MFMA]; out = agg + b2  [fp32]
    k_mgemm<64, 32, true, true><<<nblk, BS, 0, stream>>>(g1, W2, b1, dinv, h2, n);
    k_agg32<<<aggblk, BS, 0, stream>>>(h2, csr, rowptr, dinv, b2, out, n);
}

// Round 6
// 270.645 us; speedup vs baseline: 1.7716x; 1.0448x over previous
//
#include <hip/hip_runtime.h>
#include <hip/hip_fp16.h>

#define BS 256
#define BSHIFT 9                // 512 nodes per bucket
#define BNODES (1 << BSHIFT)
#define NB 256                  // bucket table size (>= ceil(100000/512)=196)
#define CHUNK 4096              // edges per block for count/scatter (16/thread)

typedef _Float16 f16x8 __attribute__((ext_vector_type(8)));
typedef float f32x4 __attribute__((ext_vector_type(4)));

// ---------------- bucketed CSR construction ----------------

__global__ __launch_bounds__(BS) void k_count(const int* __restrict__ dst,
                                              int* __restrict__ bucketCount, int E) {
    __shared__ int h[NB];
    int t = threadIdx.x;
    h[t] = 0;
    __syncthreads();
    int base = blockIdx.x * CHUNK;
#pragma unroll
    for (int j = 0; j < CHUNK / BS; ++j) {
        int e = base + j * BS + t;
        if (e < E) atomicAdd(&h[dst[e] >> BSHIFT], 1);
    }
    __syncthreads();
    if (h[t]) atomicAdd(&bucketCount[t], h[t]);
}

// 1 block, 256 threads: exclusive scan of bucketCount -> bucketBase, gcursor
__global__ void k_bucket_scan(const int* __restrict__ bucketCount,
                              int* __restrict__ bucketBase,
                              int* __restrict__ gcursor) {
    int t = threadIdx.x;
    int v = bucketCount[t];
    int incl = v;
    int lane = t & 63, w = t >> 6;
#pragma unroll
    for (int off = 1; off < 64; off <<= 1) {
        int u = __shfl_up(incl, off);
        if (lane >= off) incl += u;
    }
    __shared__ int ws[4];
    if (lane == 63) ws[w] = incl;
    __syncthreads();
    int woff = 0;
    for (int q = 0; q < w; ++q) woff += ws[q];
    int excl = woff + incl - v;
    bucketBase[t] = excl;
    gcursor[t] = excl;
    if (t == NB - 1) bucketBase[NB] = excl + v;  // == E
}

__global__ __launch_bounds__(BS) void k_scatter(const int* __restrict__ src,
                                                const int* __restrict__ dst,
                                                int* __restrict__ gcursor,
                                                int2* __restrict__ binned, int E) {
    __shared__ int h[NB];
    __shared__ int base[NB];
    int t = threadIdx.x;
    h[t] = 0;
    __syncthreads();
    int cbase = blockIdx.x * CHUNK;
    int sv[CHUNK / BS], dv[CHUNK / BS], rv[CHUNK / BS];
#pragma unroll
    for (int j = 0; j < CHUNK / BS; ++j) {
        int e = cbase + j * BS + t;
        rv[j] = -1;
        if (e < E) {
            sv[j] = src[e];
            dv[j] = dst[e];
            rv[j] = atomicAdd(&h[dv[j] >> BSHIFT], 1);
        }
    }
    __syncthreads();
    base[t] = h[t] ? atomicAdd(&gcursor[t], h[t]) : 0;
    __syncthreads();
#pragma unroll
    for (int j = 0; j < CHUNK / BS; ++j) {
        if (rv[j] >= 0) {
            int b = dv[j] >> BSHIFT;
            binned[base[b] + rv[j]] = make_int2(sv[j], dv[j]);
        }
    }
}

// one block per bucket: per-node degree from binned edges (LDS histogram)
__global__ __launch_bounds__(BS) void k_b1(const int2* __restrict__ binned,
                                           const int* __restrict__ bucketBase,
                                           int* __restrict__ deg, int n) {
    __shared__ int h[BNODES];
    int t = threadIdx.x;
    int node0 = blockIdx.x << BSHIFT;
    int nn = min(BNODES, n - node0);
#pragma unroll
    for (int i = t; i < BNODES; i += BS) h[i] = 0;
    __syncthreads();
    int eb = bucketBase[blockIdx.x], ee = bucketBase[blockIdx.x + 1];
    for (int e = eb + t; e < ee; e += BS) {
        int d = binned[e].y;
        atomicAdd(&h[d - node0], 1);
    }
    __syncthreads();
    for (int i = t; i < nn; i += BS) deg[node0 + i] = h[i] + 1;  // +1 self-loop
}

// ---------------- global scan of deg -> rowptr ----------------

__global__ void k_block_sums(const int* __restrict__ deg, int* __restrict__ bsum, int n) {
    int t = threadIdx.x;
    int base = blockIdx.x * (BS * 8) + t * 8;
    int s = 0;
#pragma unroll
    for (int j = 0; j < 8; ++j) {
        int i = base + j;
        if (i < n) s += deg[i];
    }
#pragma unroll
    for (int off = 32; off > 0; off >>= 1) s += __shfl_down(s, off);
    __shared__ int ws[BS / 64];
    int lane = t & 63, w = t >> 6;
    if (lane == 0) ws[w] = s;
    __syncthreads();
    if (t == 0) {
        int tot = 0;
        for (int q = 0; q < BS / 64; ++q) tot += ws[q];
        bsum[blockIdx.x] = tot;
    }
}

// single wave; nb <= 64 (n=100000 -> nb=49)
__global__ void k_spine(const int* __restrict__ bsum, int* __restrict__ boff,
                        int* __restrict__ total_out, int nb) {
    int t = threadIdx.x;
    int v = (t < nb) ? bsum[t] : 0;
    int incl = v;
#pragma unroll
    for (int off = 1; off < 64; off <<= 1) {
        int u = __shfl_up(incl, off);
        if (t >= off) incl += u;
    }
    if (t < nb) boff[t] = incl - v;  // exclusive
    if (t == 63) *total_out = incl;  // rowptr[n]
}

__global__ void k_scan_final(const int* __restrict__ deg, const int* __restrict__ boff,
                             int* __restrict__ rowptr, float* __restrict__ dinv, int n) {
    int t = threadIdx.x;
    int base = blockIdx.x * (BS * 8) + t * 8;
    int epre[8];
    int run = 0;
#pragma unroll
    for (int j = 0; j < 8; ++j) {
        epre[j] = run;
        int i = base + j;
        if (i < n) run += deg[i];
    }
    int lane = t & 63, w = t >> 6;
    int incl = run;
#pragma unroll
    for (int off = 1; off < 64; off <<= 1) {
        int u = __shfl_up(incl, off);
        if (lane >= off) incl += u;
    }
    __shared__ int ws[BS / 64];
    if (lane == 63) ws[w] = incl;
    __syncthreads();
    int woff = 0;
    for (int q = 0; q < w; ++q) woff += ws[q];
    int texcl = boff[blockIdx.x] + woff + (incl - run);
#pragma unroll
    for (int j = 0; j < 8; ++j) {
        int i = base + j;
        if (i < n) {
            rowptr[i] = texcl + epre[j];
            dinv[i] = rsqrtf((float)deg[i]);
        }
    }
}

// one block per bucket: fill CSR (self-loop first, then binned edges)
__global__ __launch_bounds__(BS) void k_b2(const int2* __restrict__ binned,
                                           const int* __restrict__ bucketBase,
                                           const int* __restrict__ rowptr,
                                           int* __restrict__ csr, int n) {
    __shared__ int rp[BNODES];
    __shared__ int cur[BNODES];
    int t = threadIdx.x;
    int node0 = blockIdx.x << BSHIFT;
    int nn = min(BNODES, n - node0);
#pragma unroll
    for (int i = t; i < BNODES; i += BS) cur[i] = 1;  // slot 0 = self-loop
    for (int i = t; i < nn; i += BS) {
        int r = rowptr[node0 + i];
        rp[i] = r;
        csr[r] = node0 + i;  // self-loop
    }
    __syncthreads();
    int eb = bucketBase[blockIdx.x], ee = bucketBase[blockIdx.x + 1];
    for (int e = eb + t; e < ee; e += BS) {
        int2 p = binned[e];
        int li = p.y - node0;
        int r = atomicAdd(&cur[li], 1);
        csr[rp[li] + r] = p.x;
    }
}

// ---------------- MFMA GEMM: H[i][c] = fp16(dinv[i] * sum_k act(X[i][k]) * W[k][c]) ----
// A fragments loaded DIRECTLY global->VGPR (no cross-wave A reuse; LDS round-trip was
// pure overhead: 48KB footprint capped occupancy + barrier drain). Only W^T (16/4KB)
// staged in LDS, one barrier total. Verified layouts (r5): A[m=lane&15][k=quad*8+j],
// B^T[n=lane&15][k=quad*8+j], D row=quad*4+reg col=lane&15.

template <int K, int COLS, bool FUSE, bool IN_HALF>
__global__ __launch_bounds__(BS, 4) void k_mgemm(const void* __restrict__ Xv,
                                                 const float* __restrict__ W,
                                                 const float* __restrict__ bias,
                                                 const float* __restrict__ dscale,
                                                 __half* __restrict__ H, int n) {
    constexpr int KC = K / 8;                           // 16B chunks per row
    constexpr int SWZ = (KC - 1) < 15 ? (KC - 1) : 15;  // 15 (K=128) / 7 (K=64)
    constexpr int NT = COLS / 16;                       // n-tiles per wave
    __shared__ __align__(16) _Float16 sB[COLS * K];
    int tid = threadIdx.x;

    // stage W^T (fp32 global, coalesced over c; W is tiny and L2-resident)
    for (int idx = tid; idx < COLS * KC; idx += BS) {
        int c = idx / KC, k8 = idx % KC;
        f16x8 v;
#pragma unroll
        for (int j = 0; j < 8; ++j) v[j] = (_Float16)W[(k8 * 8 + j) * COLS + c];
        *(f16x8*)&sB[c * K + ((k8 ^ (c & SWZ)) * 8)] = v;
    }
    __syncthreads();

    int w = tid >> 6, lane = tid & 63;
    int lm = lane & 15, q = lane >> 4;
    int row_m0 = blockIdx.x * 128 + w * 32;

    f32x4 acc[2][NT];
#pragma unroll
    for (int tm = 0; tm < 2; ++tm)
#pragma unroll
        for (int tn = 0; tn < NT; ++tn) acc[tm][tn] = (f32x4){0.f, 0.f, 0.f, 0.f};

#pragma unroll
    for (int kk = 0; kk < K / 32; ++kk) {
        int k0 = kk * 32 + q * 8;
        f16x8 af[2], bf[NT];
#pragma unroll
        for (int tm = 0; tm < 2; ++tm) {
            int row = row_m0 + tm * 16 + lm;
            int rl = row < n ? row : (n - 1);  // clamp: keep loads in-bounds, values unused
            if (IN_HALF) {
                f16x8 raw = *(const f16x8*)((const _Float16*)Xv + (size_t)rl * K + k0);
                if (FUSE) {
                    const float4* bp = (const float4*)(bias + k0);
                    float4 ba = bp[0], bb = bp[1];
                    float f[8] = {(float)raw[0], (float)raw[1], (float)raw[2], (float)raw[3],
                                  (float)raw[4], (float)raw[5], (float)raw[6], (float)raw[7]};
                    f[0] = fmaxf(f[0] + ba.x, 0.f); f[1] = fmaxf(f[1] + ba.y, 0.f);
                    f[2] = fmaxf(f[2] + ba.z, 0.f); f[3] = fmaxf(f[3] + ba.w, 0.f);
                    f[4] = fmaxf(f[4] + bb.x, 0.f); f[5] = fmaxf(f[5] + bb.y, 0.f);
                    f[6] = fmaxf(f[6] + bb.z, 0.f); f[7] = fmaxf(f[7] + bb.w, 0.f);
#pragma unroll
                    for (int j = 0; j < 8; ++j) raw[j] = (_Float16)f[j];
                }
                af[tm] = raw;
            } else {
                const float4* xp = (const float4*)Xv + ((size_t)rl * K + k0) / 4;
                float4 a = xp[0], b = xp[1];
                f16x8 v;
                v[0] = (_Float16)a.x; v[1] = (_Float16)a.y;
                v[2] = (_Float16)a.z; v[3] = (_Float16)a.w;
                v[4] = (_Float16)b.x; v[5] = (_Float16)b.y;
                v[6] = (_Float16)b.z; v[7] = (_Float16)b.w;
                af[tm] = v;
            }
        }
#pragma unroll
        for (int tn = 0; tn < NT; ++tn) {
            int c = tn * 16 + lm;
            bf[tn] = *(const f16x8*)&sB[c * K + (((kk * 4 + q) ^ (c & SWZ)) * 8)];
        }
#pragma unroll
        for (int tm = 0; tm < 2; ++tm)
#pragma unroll
            for (int tn = 0; tn < NT; ++tn)
                acc[tm][tn] = __builtin_amdgcn_mfma_f32_16x16x32_f16(af[tm], bf[tn],
                                                                     acc[tm][tn], 0, 0, 0);
    }

#pragma unroll
    for (int tm = 0; tm < 2; ++tm) {
#pragma unroll
        for (int r = 0; r < 4; ++r) {
            int row = row_m0 + tm * 16 + q * 4 + r;
            if (row < n) {
                float dv = dscale[row];
#pragma unroll
                for (int tn = 0; tn < NT; ++tn) {
                    int col = tn * 16 + lm;
                    H[(size_t)row * COLS + col] = __float2half_rn(acc[tm][tn][r] * dv);
                }
            }
        }
    }
}

// ---------------- Aggregation (gather-side, no atomics; h in fp16) ----------------
// Two nodes per wave (32 lanes each): two independent latency chains amortize the
// serial rowptr->csr->gather rounds. Within a half: 2 edges/iter x 16 lanes x 8B.

__global__ __launch_bounds__(BS) void k_agg64(const __half* __restrict__ h,
                                              const int* __restrict__ csr,
                                              const int* __restrict__ rowptr,
                                              const float* __restrict__ dinv,
                                              __half* __restrict__ out, int n) {
    int wid = (blockIdx.x * BS + threadIdx.x) >> 6;
    int lane = threadIdx.x & 63;
    int half = lane >> 5, hl = lane & 31;
    int node = wid * 2 + half;
    bool valid = node < n;
    int b = 0, e = 0;
    if (valid) { b = rowptr[node]; e = rowptr[node + 1]; }
    int slot = hl >> 4, fq = hl & 15;  // edge slot 0..1, feature quad 0..15
    float a0 = 0.f, a1 = 0.f, a2 = 0.f, a3 = 0.f;
    for (int c = b; c < e; c += 32) {
        int m = e - c;
        if (m > 32) m = 32;
        int sv = (hl < m) ? csr[c + hl] : 0;
        for (int j = 0; j < m; j += 2) {
            int js = j + slot;
            int s = __shfl(sv, js < m ? js : 0, 32);
            if (js < m) {
                float2 raw = *(const float2*)(h + (size_t)s * 64 + fq * 4);
                __half2 h0 = ((const __half2*)&raw)[0], h1 = ((const __half2*)&raw)[1];
                float2 f0 = __half22float2(h0), f1 = __half22float2(h1);
                a0 += f0.x; a1 += f0.y; a2 += f1.x; a3 += f1.y;
            }
        }
    }
    // reduce the two slots within each half (delta 16 stays inside the half for hl<16)
    a0 += __shfl_down(a0, 16); a1 += __shfl_down(a1, 16);
    a2 += __shfl_down(a2, 16); a3 += __shfl_down(a3, 16);
    if (valid && hl < 16) {
        float dv = dinv[node];
        union { __half2 h2[2]; float2 f2; } pk;
        pk.h2[0] = __floats2half2_rn(a0 * dv, a1 * dv);
        pk.h2[1] = __floats2half2_rn(a2 * dv, a3 * dv);
        *(float2*)(out + (size_t)node * 64 + hl * 4) = pk.f2;
    }
}

// 32 features: two nodes per wave, 4 edges/iter per half (8 lanes/edge); fp32 out + bias.
__global__ __launch_bounds__(BS) void k_agg32(const __half* __restrict__ h,
                                              const int* __restrict__ csr,
                                              const int* __restrict__ rowptr,
                                              const float* __restrict__ dinv,
                                              const float* __restrict__ bias,
                                              float* __restrict__ out, int n) {
    int wid = (blockIdx.x * BS + threadIdx.x) >> 6;
    int lane = threadIdx.x & 63;
    int half = lane >> 5, hl = lane & 31;
    int node = wid * 2 + half;
    bool valid = node < n;
    int b = 0, e = 0;
    if (valid) { b = rowptr[node]; e = rowptr[node + 1]; }
    int slot = hl >> 3, fq = hl & 7;  // edge slot 0..3, feature quad 0..7
    float a0 = 0.f, a1 = 0.f, a2 = 0.f, a3 = 0.f;
    for (int c = b; c < e; c += 32) {
        int m = e - c;
        if (m > 32) m = 32;
        int sv = (hl < m) ? csr[c + hl] : 0;
        for (int j = 0; j < m; j += 4) {
            int js = j + slot;
            int s = __shfl(sv, js < m ? js : 0, 32);
            if (js < m) {
                float2 raw = *(const float2*)(h + (size_t)s * 32 + fq * 4);
                __half2 h0 = ((const __half2*)&raw)[0], h1 = ((const __half2*)&raw)[1];
                float2 f0 = __half22float2(h0), f1 = __half22float2(h1);
                a0 += f0.x; a1 += f0.y; a2 += f1.x; a3 += f1.y;
            }
        }
    }
    a0 += __shfl_down(a0, 16); a1 += __shfl_down(a1, 16);
    a2 += __shfl_down(a2, 16); a3 += __shfl_down(a3, 16);
    a0 += __shfl_down(a0, 8);  a1 += __shfl_down(a1, 8);
    a2 += __shfl_down(a2, 8);  a3 += __shfl_down(a3, 8);
    if (valid && hl < 8) {
        float dv = dinv[node];
        float4 bv = ((const float4*)bias)[hl];
        float4 o = make_float4(a0 * dv + bv.x, a1 * dv + bv.y,
                               a2 * dv + bv.z, a3 * dv + bv.w);
        ((float4*)(out + (size_t)node * 32))[hl] = o;
    }
}

// ---------------- launch ----------------

extern "C" void kernel_launch(void* const* d_in, const int* in_sizes, int n_in,
                              void* d_out, int out_size, void* d_ws, size_t ws_size,
                              hipStream_t stream) {
    const float* x  = (const float*)d_in[0];
    const int* eidx = (const int*)d_in[1];
    const float* W1 = (const float*)d_in[2];
    const float* b1 = (const float*)d_in[3];
    const float* W2 = (const float*)d_in[4];
    const float* b2 = (const float*)d_in[5];
    float* out = (float*)d_out;

    int n = in_sizes[0] / 128;
    int E = in_sizes[1] / 2;
    const int* srcA = eidx;
    const int* dstA = eidx + E;

    char* p = (char*)d_ws;
    auto alloc = [&](size_t bytes) {
        char* q = p;
        p += (bytes + 255) & ~(size_t)255;
        return q;
    };
    int*    deg     = (int*)alloc((size_t)n * 4);
    int*    rowptr  = (int*)alloc((size_t)(n + 1) * 4);
    int*    bsum    = (int*)alloc(64 * 4);
    int*    boff    = (int*)alloc(64 * 4);
    float*  dinv    = (float*)alloc((size_t)n * 4);
    int*    bcount  = (int*)alloc(NB * 4);
    int*    bbase   = (int*)alloc((NB + 1) * 4);
    int*    gcursor = (int*)alloc(NB * 4);
    int2*   binned  = (int2*)alloc((size_t)E * 8);
    int*    csr     = (int*)alloc((size_t)(E + n) * 4);
    __half* h1      = (__half*)alloc((size_t)n * 64 * 2);
    __half* g1      = (__half*)alloc((size_t)n * 64 * 2);
    __half* h2      = (__half*)alloc((size_t)n * 32 * 2);

    int nb_scan  = (n + BS * 8 - 1) / (BS * 8);   // 49 (<=64 req'd by k_spine)
    int nchunks  = (E + CHUNK - 1) / CHUNK;       // 391
    int nbuckets = (n + BNODES - 1) / BNODES;     // 196 (<= NB)
    int nblk     = (n + 127) / 128;               // 782 MFMA-GEMM tiles
    int npairs   = (n + 1) / 2;                   // 2 nodes per wave
    int aggblk   = (int)(((size_t)npairs * 64 + BS - 1) / BS);

    hipMemsetAsync(bcount, 0, NB * 4, stream);
    k_count<<<nchunks, BS, 0, stream>>>(dstA, bcount, E);
    k_bucket_scan<<<1, BS, 0, stream>>>(bcount, bbase, gcursor);
    k_scatter<<<nchunks, BS, 0, stream>>>(srcA, dstA, gcursor, binned, E);
    k_b1<<<nbuckets, BS, 0, stream>>>(binned, bbase, deg, n);
    k_block_sums<<<nb_scan, BS, 0, stream>>>(deg, bsum, n);
    k_spine<<<1, 64, 0, stream>>>(bsum, boff, rowptr + n, nb_scan);
    k_scan_final<<<nb_scan, BS, 0, stream>>>(deg, boff, rowptr, dinv, n);
    k_b2<<<nbuckets, BS, 0, stream>>>(binned, bbase, rowptr, csr, n);

    // layer 1: h1 = dinv .* (x @ W1)  [fp16 MFMA, direct-A]; g1 = dinv .* (A-gather h1)
    k_mgemm<128, 64, false, false><<<nblk, BS, 0, stream>>>(x, W1, nullptr, dinv, h1, n);
    k_agg64<<<aggblk, BS, 0, stream>>>(h1, csr, rowptr, dinv, g1, n);

    // layer 2: h2 = dinv .* (relu(g1 + b1) @ W2)  [fp16 MFMA, fused act]; out = agg + b2
    k_mgemm<64, 32, true, true><<<nblk, BS, 0, stream>>>(g1, W2, b1, dinv, h2, n);
    k_agg32<<<aggblk, BS, 0, stream>>>(h2, csr, rowptr, dinv, b2, out, n);
}

// Round 7
// 241.064 us; speedup vs baseline: 1.9890x; 1.1227x over previous
//
#include <hip/hip_runtime.h>
#include <hip/hip_fp16.h>

#define BS 256
#define BSHIFT 9                // 512 nodes per bucket
#define BNODES (1 << BSHIFT)
#define NB 256                  // bucket table size (>= ceil(100000/512)=196)
#define CHUNK 4096              // edges per block for count/scatter (16/thread)
// binned edge packing: src in bits [0,17), local dst in bits [17,26). Requires n <= 2^17.

typedef _Float16 f16x8 __attribute__((ext_vector_type(8)));
typedef float f32x4 __attribute__((ext_vector_type(4)));

// ---------------- bucketed CSR construction ----------------

__global__ __launch_bounds__(BS) void k_count(const int* __restrict__ dst,
                                              int* __restrict__ bucketCount, int E) {
    __shared__ int h[NB];
    int t = threadIdx.x;
    h[t] = 0;
    __syncthreads();
    int base = blockIdx.x * CHUNK;
#pragma unroll
    for (int j = 0; j < CHUNK / BS; ++j) {
        int e = base + j * BS + t;
        if (e < E) atomicAdd(&h[dst[e] >> BSHIFT], 1);
    }
    __syncthreads();
    if (h[t]) atomicAdd(&bucketCount[t], h[t]);
}

// 1 block, 256 threads: exclusive scan of bucketCount -> bucketBase, gcursor
__global__ void k_bucket_scan(const int* __restrict__ bucketCount,
                              int* __restrict__ bucketBase,
                              int* __restrict__ gcursor) {
    int t = threadIdx.x;
    int v = bucketCount[t];
    int incl = v;
    int lane = t & 63, w = t >> 6;
#pragma unroll
    for (int off = 1; off < 64; off <<= 1) {
        int u = __shfl_up(incl, off);
        if (lane >= off) incl += u;
    }
    __shared__ int ws[4];
    if (lane == 63) ws[w] = incl;
    __syncthreads();
    int woff = 0;
    for (int q = 0; q < w; ++q) woff += ws[q];
    int excl = woff + incl - v;
    bucketBase[t] = excl;
    gcursor[t] = excl;
    if (t == NB - 1) bucketBase[NB] = excl + v;  // == E
}

__global__ __launch_bounds__(BS) void k_scatter(const int* __restrict__ src,
                                                const int* __restrict__ dst,
                                                int* __restrict__ gcursor,
                                                int* __restrict__ binned, int E) {
    __shared__ int h[NB];
    __shared__ int base[NB];
    int t = threadIdx.x;
    h[t] = 0;
    __syncthreads();
    int cbase = blockIdx.x * CHUNK;
    int sv[CHUNK / BS], dv[CHUNK / BS], rv[CHUNK / BS];
#pragma unroll
    for (int j = 0; j < CHUNK / BS; ++j) {
        int e = cbase + j * BS + t;
        rv[j] = -1;
        if (e < E) {
            sv[j] = src[e];
            dv[j] = dst[e];
            rv[j] = atomicAdd(&h[dv[j] >> BSHIFT], 1);
        }
    }
    __syncthreads();
    base[t] = h[t] ? atomicAdd(&gcursor[t], h[t]) : 0;
    __syncthreads();
#pragma unroll
    for (int j = 0; j < CHUNK / BS; ++j) {
        if (rv[j] >= 0) {
            int b = dv[j] >> BSHIFT;
            // pack src + local dst (n <= 2^17 for this problem: n = 100000)
            binned[base[b] + rv[j]] = sv[j] | ((dv[j] & (BNODES - 1)) << 17);
        }
    }
}

// one block per bucket: degree histogram -> LDS exclusive scan -> rowptr/dinv ->
// CSR fill. rowptr[v] = bucketBase[b] + local_excl(v) + v (each node < v adds 1 self-loop).
__global__ __launch_bounds__(BS) void k_build(const int* __restrict__ binned,
                                              const int* __restrict__ bucketBase,
                                              int* __restrict__ rowptr,
                                              float* __restrict__ dinv,
                                              int* __restrict__ csr, int n, int E) {
    __shared__ int h[BNODES];
    __shared__ int rp[BNODES];
    __shared__ int cur[BNODES];
    __shared__ int ws[4];
    int t = threadIdx.x;
    int bkt = blockIdx.x;
    int node0 = bkt << BSHIFT;
    int nn = min(BNODES, n - node0);
#pragma unroll
    for (int i = t; i < BNODES; i += BS) h[i] = 0;
    __syncthreads();
    int eb = bucketBase[bkt], ee = bucketBase[bkt + 1];
    for (int e = eb + t; e < ee; e += BS)
        atomicAdd(&h[binned[e] >> 17], 1);
    __syncthreads();
    // exclusive scan of h[0..512): each thread owns 2 elements
    int i0 = 2 * t;
    int v0 = h[i0], v1 = h[i0 + 1];
    int pair = v0 + v1;
    int lane = t & 63, w = t >> 6;
    int incl = pair;
#pragma unroll
    for (int off = 1; off < 64; off <<= 1) {
        int u = __shfl_up(incl, off);
        if (lane >= off) incl += u;
    }
    if (lane == 63) ws[w] = incl;
    __syncthreads();
    int woff = 0;
    for (int q = 0; q < w; ++q) woff += ws[q];
    int excl = woff + incl - pair;  // edges before node i0 within bucket
    int r0 = eb + node0 + excl + i0;
    int r1 = r0 + v0 + 1;
    rp[i0] = r0; rp[i0 + 1] = r1;
    cur[i0] = 1; cur[i0 + 1] = 1;  // slot 0 = self-loop
    if (i0 < nn) {
        rowptr[node0 + i0] = r0;
        dinv[node0 + i0] = rsqrtf((float)(v0 + 1));
        csr[r0] = node0 + i0;
    }
    if (i0 + 1 < nn) {
        rowptr[node0 + i0 + 1] = r1;
        dinv[node0 + i0 + 1] = rsqrtf((float)(v1 + 1));
        csr[r1] = node0 + i0 + 1;
    }
    if (bkt == 0 && t == 0) rowptr[n] = E + n;
    __syncthreads();
    for (int e = eb + t; e < ee; e += BS) {
        int p = binned[e];
        int li = p >> 17;
        int r = atomicAdd(&cur[li], 1);
        csr[rp[li] + r] = p & 0x1FFFF;
    }
}

// ---------------- MFMA GEMM: H[i][c] = fp16(dinv[i] * sum_k act(X[i][k]) * W[k][c]) ----
// A fragments loaded DIRECTLY global->VGPR (no cross-wave A reuse). Only W^T staged
// in LDS, one barrier total. Layouts (verified r5): A[m=lane&15][k=quad*8+j],
// B^T[n=lane&15][k=quad*8+j], D row=quad*4+reg col=lane&15.

template <int K, int COLS, bool FUSE, bool IN_HALF>
__global__ __launch_bounds__(BS, 4) void k_mgemm(const void* __restrict__ Xv,
                                                 const float* __restrict__ W,
                                                 const float* __restrict__ bias,
                                                 const float* __restrict__ dscale,
                                                 __half* __restrict__ H, int n) {
    constexpr int KC = K / 8;                           // 16B chunks per row
    constexpr int SWZ = (KC - 1) < 15 ? (KC - 1) : 15;  // 15 (K=128) / 7 (K=64)
    constexpr int NT = COLS / 16;                       // n-tiles per wave
    __shared__ __align__(16) _Float16 sB[COLS * K];
    int tid = threadIdx.x;

    // stage W^T (fp32 global; W is tiny and L2-resident)
    for (int idx = tid; idx < COLS * KC; idx += BS) {
        int c = idx / KC, k8 = idx % KC;
        f16x8 v;
#pragma unroll
        for (int j = 0; j < 8; ++j) v[j] = (_Float16)W[(k8 * 8 + j) * COLS + c];
        *(f16x8*)&sB[c * K + ((k8 ^ (c & SWZ)) * 8)] = v;
    }
    __syncthreads();

    int w = tid >> 6, lane = tid & 63;
    int lm = lane & 15, q = lane >> 4;
    int row_m0 = blockIdx.x * 128 + w * 32;

    f32x4 acc[2][NT];
#pragma unroll
    for (int tm = 0; tm < 2; ++tm)
#pragma unroll
        for (int tn = 0; tn < NT; ++tn) acc[tm][tn] = (f32x4){0.f, 0.f, 0.f, 0.f};

#pragma unroll
    for (int kk = 0; kk < K / 32; ++kk) {
        int k0 = kk * 32 + q * 8;
        f16x8 af[2], bf[NT];
#pragma unroll
        for (int tm = 0; tm < 2; ++tm) {
            int row = row_m0 + tm * 16 + lm;
            int rl = row < n ? row : (n - 1);  // clamp: keep loads in-bounds, values unused
            if (IN_HALF) {
                f16x8 raw = *(const f16x8*)((const _Float16*)Xv + (size_t)rl * K + k0);
                if (FUSE) {
                    const float4* bp = (const float4*)(bias + k0);
                    float4 ba = bp[0], bb = bp[1];
                    float f[8] = {(float)raw[0], (float)raw[1], (float)raw[2], (float)raw[3],
                                  (float)raw[4], (float)raw[5], (float)raw[6], (float)raw[7]};
                    f[0] = fmaxf(f[0] + ba.x, 0.f); f[1] = fmaxf(f[1] + ba.y, 0.f);
                    f[2] = fmaxf(f[2] + ba.z, 0.f); f[3] = fmaxf(f[3] + ba.w, 0.f);
                    f[4] = fmaxf(f[4] + bb.x, 0.f); f[5] = fmaxf(f[5] + bb.y, 0.f);
                    f[6] = fmaxf(f[6] + bb.z, 0.f); f[7] = fmaxf(f[7] + bb.w, 0.f);
#pragma unroll
                    for (int j = 0; j < 8; ++j) raw[j] = (_Float16)f[j];
                }
                af[tm] = raw;
            } else {
                const float4* xp = (const float4*)Xv + ((size_t)rl * K + k0) / 4;
                float4 a = xp[0], b = xp[1];
                f16x8 v;
                v[0] = (_Float16)a.x; v[1] = (_Float16)a.y;
                v[2] = (_Float16)a.z; v[3] = (_Float16)a.w;
                v[4] = (_Float16)b.x; v[5] = (_Float16)b.y;
                v[6] = (_Float16)b.z; v[7] = (_Float16)b.w;
                af[tm] = v;
            }
        }
#pragma unroll
        for (int tn = 0; tn < NT; ++tn) {
            int c = tn * 16 + lm;
            bf[tn] = *(const f16x8*)&sB[c * K + (((kk * 4 + q) ^ (c & SWZ)) * 8)];
        }
#pragma unroll
        for (int tm = 0; tm < 2; ++tm)
#pragma unroll
            for (int tn = 0; tn < NT; ++tn)
                acc[tm][tn] = __builtin_amdgcn_mfma_f32_16x16x32_f16(af[tm], bf[tn],
                                                                     acc[tm][tn], 0, 0, 0);
    }

#pragma unroll
    for (int tm = 0; tm < 2; ++tm) {
#pragma unroll
        for (int r = 0; r < 4; ++r) {
            int row = row_m0 + tm * 16 + q * 4 + r;
            if (row < n) {
                float dv = dscale[row];
#pragma unroll
                for (int tn = 0; tn < NT; ++tn) {
                    int col = tn * 16 + lm;
                    H[(size_t)row * COLS + col] = __float2half_rn(acc[tm][tn][r] * dv);
                }
            }
        }
    }
}

// ---------------- Aggregation (gather-side, no atomics; h in fp16) ----------------
// Two nodes per wave; per 32-lane half: 8 edges per iteration (4 independent float2
// gathers in flight) to raise latency-hiding concurrency (r6: ~2 loads/wave in flight
// capped the pipe at 2.2 TB/s).

__device__ __forceinline__ void acc_h4(float2 raw, float& x0, float& x1,
                                       float& x2, float& x3) {
    __half2 u0 = ((const __half2*)&raw)[0], u1 = ((const __half2*)&raw)[1];
    float2 f0 = __half22float2(u0), f1 = __half22float2(u1);
    x0 += f0.x; x1 += f0.y; x2 += f1.x; x3 += f1.y;
}

__global__ __launch_bounds__(BS) void k_agg64(const __half* __restrict__ h,
                                              const int* __restrict__ csr,
                                              const int* __restrict__ rowptr,
                                              const float* __restrict__ dinv,
                                              __half* __restrict__ out, int n) {
    int wid = (blockIdx.x * BS + threadIdx.x) >> 6;
    int lane = threadIdx.x & 63;
    int half = lane >> 5, hl = lane & 31;
    int node = wid * 2 + half;
    bool valid = node < n;
    int b = 0, e = 0;
    if (valid) { b = rowptr[node]; e = rowptr[node + 1]; }
    int slot = hl >> 4, fq = hl & 15;  // edge slot 0..1, feature quad 0..15
    float a0 = 0.f, a1 = 0.f, a2 = 0.f, a3 = 0.f;
    float c0 = 0.f, c1 = 0.f, c2 = 0.f, c3 = 0.f;
    for (int c = b; c < e; c += 32) {
        int m = e - c;
        if (m > 32) m = 32;
        int sv = (hl < m) ? csr[c + hl] : 0;
        int j = 0;
        for (; j + 7 < m; j += 8) {
            int sA = __shfl(sv, j + slot, 32);
            int sB = __shfl(sv, j + 2 + slot, 32);
            int sC = __shfl(sv, j + 4 + slot, 32);
            int sD = __shfl(sv, j + 6 + slot, 32);
            float2 rA = *(const float2*)(h + (size_t)sA * 64 + fq * 4);
            float2 rB = *(const float2*)(h + (size_t)sB * 64 + fq * 4);
            float2 rC = *(const float2*)(h + (size_t)sC * 64 + fq * 4);
            float2 rD = *(const float2*)(h + (size_t)sD * 64 + fq * 4);
            acc_h4(rA, a0, a1, a2, a3);
            acc_h4(rB, c0, c1, c2, c3);
            acc_h4(rC, a0, a1, a2, a3);
            acc_h4(rD, c0, c1, c2, c3);
        }
        for (; j < m; j += 2) {
            int js = j + slot;
            int s = __shfl(sv, js < m ? js : 0, 32);
            if (js < m) {
                float2 raw = *(const float2*)(h + (size_t)s * 64 + fq * 4);
                acc_h4(raw, a0, a1, a2, a3);
            }
        }
    }
    a0 += c0; a1 += c1; a2 += c2; a3 += c3;
    a0 += __shfl_down(a0, 16); a1 += __shfl_down(a1, 16);
    a2 += __shfl_down(a2, 16); a3 += __shfl_down(a3, 16);
    if (valid && hl < 16) {
        float dv = dinv[node];
        union { __half2 h2[2]; float2 f2; } pk;
        pk.h2[0] = __floats2half2_rn(a0 * dv, a1 * dv);
        pk.h2[1] = __floats2half2_rn(a2 * dv, a3 * dv);
        *(float2*)(out + (size_t)node * 64 + hl * 4) = pk.f2;
    }
}

// 32 features: two nodes per wave, 16 edges/iter per half (4 gathers in flight).
__global__ __launch_bounds__(BS) void k_agg32(const __half* __restrict__ h,
                                              const int* __restrict__ csr,
                                              const int* __restrict__ rowptr,
                                              const float* __restrict__ dinv,
                                              const float* __restrict__ bias,
                                              float* __restrict__ out, int n) {
    int wid = (blockIdx.x * BS + threadIdx.x) >> 6;
    int lane = threadIdx.x & 63;
    int half = lane >> 5, hl = lane & 31;
    int node = wid * 2 + half;
    bool valid = node < n;
    int b = 0, e = 0;
    if (valid) { b = rowptr[node]; e = rowptr[node + 1]; }
    int slot = hl >> 3, fq = hl & 7;  // edge slot 0..3, feature quad 0..7
    float a0 = 0.f, a1 = 0.f, a2 = 0.f, a3 = 0.f;
    float c0 = 0.f, c1 = 0.f, c2 = 0.f, c3 = 0.f;
    for (int c = b; c < e; c += 32) {
        int m = e - c;
        if (m > 32) m = 32;
        int sv = (hl < m) ? csr[c + hl] : 0;
        int j = 0;
        for (; j + 15 < m; j += 16) {
            int sA = __shfl(sv, j + slot, 32);
            int sB = __shfl(sv, j + 4 + slot, 32);
            int sC = __shfl(sv, j + 8 + slot, 32);
            int sD = __shfl(sv, j + 12 + slot, 32);
            float2 rA = *(const float2*)(h + (size_t)sA * 32 + fq * 4);
            float2 rB = *(const float2*)(h + (size_t)sB * 32 + fq * 4);
            float2 rC = *(const float2*)(h + (size_t)sC * 32 + fq * 4);
            float2 rD = *(const float2*)(h + (size_t)sD * 32 + fq * 4);
            acc_h4(rA, a0, a1, a2, a3);
            acc_h4(rB, c0, c1, c2, c3);
            acc_h4(rC, a0, a1, a2, a3);
            acc_h4(rD, c0, c1, c2, c3);
        }
        for (; j < m; j += 4) {
            int js = j + slot;
            int s = __shfl(sv, js < m ? js : 0, 32);
            if (js < m) {
                float2 raw = *(const float2*)(h + (size_t)s * 32 + fq * 4);
                acc_h4(raw, a0, a1, a2, a3);
            }
        }
    }
    a0 += c0; a1 += c1; a2 += c2; a3 += c3;
    a0 += __shfl_down(a0, 16); a1 += __shfl_down(a1, 16);
    a2 += __shfl_down(a2, 16); a3 += __shfl_down(a3, 16);
    a0 += __shfl_down(a0, 8);  a1 += __shfl_down(a1, 8);
    a2 += __shfl_down(a2, 8);  a3 += __shfl_down(a3, 8);
    if (valid && hl < 8) {
        float dv = dinv[node];
        float4 bv = ((const float4*)bias)[hl];
        float4 o = make_float4(a0 * dv + bv.x, a1 * dv + bv.y,
                               a2 * dv + bv.z, a3 * dv + bv.w);
        ((float4*)(out + (size_t)node * 32))[hl] = o;
    }
}

// ---------------- launch ----------------

extern "C" void kernel_launch(void* const* d_in, const int* in_sizes, int n_in,
                              void* d_out, int out_size, void* d_ws, size_t ws_size,
                              hipStream_t stream) {
    const float* x  = (const float*)d_in[0];
    const int* eidx = (const int*)d_in[1];
    const float* W1 = (const float*)d_in[2];
    const float* b1 = (const float*)d_in[3];
    const float* W2 = (const float*)d_in[4];
    const float* b2 = (const float*)d_in[5];
    float* out = (float*)d_out;

    int n = in_sizes[0] / 128;
    int E = in_sizes[1] / 2;
    const int* srcA = eidx;
    const int* dstA = eidx + E;

    char* p = (char*)d_ws;
    auto alloc = [&](size_t bytes) {
        char* q = p;
        p += (bytes + 255) & ~(size_t)255;
        return q;
    };
    int*    rowptr  = (int*)alloc((size_t)(n + 1) * 4);
    float*  dinv    = (float*)alloc((size_t)n * 4);
    int*    bcount  = (int*)alloc(NB * 4);
    int*    bbase   = (int*)alloc((NB + 1) * 4);
    int*    gcursor = (int*)alloc(NB * 4);
    int*    binned  = (int*)alloc((size_t)E * 4);
    int*    csr     = (int*)alloc((size_t)(E + n) * 4);
    __half* h1      = (__half*)alloc((size_t)n * 64 * 2);
    __half* g1      = (__half*)alloc((size_t)n * 64 * 2);
    __half* h2      = (__half*)alloc((size_t)n * 32 * 2);

    int nchunks  = (E + CHUNK - 1) / CHUNK;       // 391
    int nbuckets = (n + BNODES - 1) / BNODES;     // 196 (<= NB)
    int nblk     = (n + 127) / 128;               // 782 MFMA-GEMM tiles
    int npairs   = (n + 1) / 2;                   // 2 nodes per wave
    int aggblk   = (int)(((size_t)npairs * 64 + BS - 1) / BS);

    hipMemsetAsync(bcount, 0, NB * 4, stream);
    k_count<<<nchunks, BS, 0, stream>>>(dstA, bcount, E);
    k_bucket_scan<<<1, BS, 0, stream>>>(bcount, bbase, gcursor);
    k_scatter<<<nchunks, BS, 0, stream>>>(srcA, dstA, gcursor, binned, E);
    k_build<<<nbuckets, BS, 0, stream>>>(binned, bbase, rowptr, dinv, csr, n, E);

    // layer 1: h1 = dinv .* (x @ W1)  [fp16 MFMA, direct-A]; g1 = dinv .* (A-gather h1)
    k_mgemm<128, 64, false, false><<<nblk, BS, 0, stream>>>(x, W1, nullptr, dinv, h1, n);
    k_agg64<<<aggblk, BS, 0, stream>>>(h1, csr, rowptr, dinv, g1, n);

    // layer 2: h2 = dinv .* (relu(g1 + b1) @ W2)  [fp16 MFMA, fused act]; out = agg + b2
    k_mgemm<64, 32, true, true><<<nblk, BS, 0, stream>>>(g1, W2, b1, dinv, h2, n);
    k_agg32<<<aggblk, BS, 0, stream>>>(h2, csr, rowptr, dinv, b2, out, n);
}